// Round 9
// baseline (556.553 us; speedup 1.0000x reference)
//
#include <hip/hip_runtime.h>
#include <hip/hip_fp16.h>
#include <hip/hip_cooperative_groups.h>
#include <math.h>

namespace cg = cooperative_groups;

#define D_ 128
#define K_ 1024
#define N_ 65536
#define DECAY_ 0.99f
#define OMD_ 0.01f
#define EPS_ 1e-5f
#define VQC_ 0.25f
#define M1_ 0.14f     // pair band: 2*eps(fp16 dot) + 2*keytrunc
#define M2_ 0.14f     // triple band -> full K rescan
#define BIAS_ 96.0f   // positivity shift for e2-2xe (argmin-invariant per token)
#define CLMIN_ 0.5f
#define CLMAX_ 508.0f // keys < 512 => trunc ULP 2^-5; clamped => triple-flagged
#define WSEG 32       // tokens per coop-segdeq block (uniform work)
#define CBLK 2048     // cooperative grid (x 128 thr): 8 blk/CU, 16 waves/CU

typedef __attribute__((ext_vector_type(8))) _Float16 half8;
typedef __attribute__((ext_vector_type(4))) float f32x4;

// ---- workspace offsets (in 4-byte elements) ----
#define WOFF_CODE  0          // int[65536]
#define WOFF_E2    65536      // float[1024]
#define WOFF_CNT   66560      // int[1024]
#define WOFF_SSQ   67584      // float[1]  (zeroed by k_prep block 0)
#define WOFF_RCNT  67585      // int[1]    (CNT..RCNT zeroed by k_prep block 0)
#define WOFF_BASE  67648      // int[1025] (unused now)
#define WOFF_CURS  68736      // int[1024] zero-based scatter cursor (zeroed by prep)
#define WOFF_ORDER 69760      // int[65536]
#define WOFF_ET    136320     // float[131072] (K x D), 16B aligned
#define WOFF_PART  267392     // float[131072] (K x D) atomic segment sums
#define WOFF_CSORT 398464     // int[65536] code of each sorted slot
#define WOFF_RLIST 791680     // int[65536]
#define WOFF_EF    857216     // ushort[131072] frag-ordered fp16 of -2E

// ---- output offsets (in floats), reference return order ----
#define OOFF_Q     0          // [16,4096,128]
#define OOFF_DIFF  8388608    // scalar
#define OOFF_CODE  8388609    // [16,4096]
#define OOFF_NEMB  8454145    // [128,1024]
#define OOFF_NCS   8585217    // [1024]
#define OOFF_NMEAN 8586241    // [128,1024]

__device__ __forceinline__ unsigned umin32(unsigned a, unsigned b) { return a < b ? a : b; }
__device__ __forceinline__ unsigned umax32(unsigned a, unsigned b) { return a > b ? a : b; }

// async global->LDS 16B per lane (direct DMA, no VGPR round-trip)
__device__ __forceinline__ void gld16(const unsigned short* g, unsigned short* l) {
    __builtin_amdgcn_global_load_lds(
        (const __attribute__((address_space(1))) unsigned int*)g,
        (__attribute__((address_space(3))) unsigned int*)l, 16, 0, 0);
}

// -------------------------------------------------------------------
// Fused prep: E [D][K] -> Et [K][D], fp16 frag plane Ef of -2E, e2,
// cnt/ssq/rcnt zeroing (block 0), zc zeroing (block 1), part1 zeroing.
__launch_bounds__(256)
__global__ void k_prep(const float* __restrict__ E, float* __restrict__ Et,
                       unsigned short* __restrict__ Ef, float* __restrict__ e2,
                       int* __restrict__ cnt, int* __restrict__ zc,
                       float* __restrict__ part1) {
    __shared__ float tile[128 * 17];   // tile[d][cc], pad 17 vs 16
    __shared__ float e2s[16];
    int tid = threadIdx.x;
    int b = blockIdx.x;                // 0..63
    int c0 = b * 16;
    if (b == 0) {
        for (int i = tid; i < 1026; i += 256) cnt[i] = 0;   // cnt[1024], ssq, rcnt
    }
    if (b == 1) {
        for (int i = tid; i < 1024; i += 256) zc[i] = 0;    // scatter cursor
    }
    // zero part1 (K*D floats, 2048 per block)
    #pragma unroll
    for (int i = 0; i < 8; ++i) part1[b * 2048 + i * 256 + tid] = 0.f;
    if (tid < 16) e2s[tid] = 0.f;
    // ---- load E columns c0..c0+15 (2048 floats) ----
    #pragma unroll
    for (int i = 0; i < 8; ++i) {
        int idx = i * 256 + tid;       // 0..2047
        int d = idx >> 4, cc = idx & 15;
        tile[d * 17 + cc] = E[d * K_ + c0 + cc];
    }
    __syncthreads();
    // ---- write Et rows (coalesced, conflict-free via pad) ----
    #pragma unroll
    for (int i = 0; i < 8; ++i) {
        int idx = i * 256 + tid;
        int cc = idx >> 7, d = idx & 127;
        Et[(size_t)(c0 + cc) * D_ + d] = tile[d * 17 + cc];
    }
    // ---- Ef frags + e2 ----
    int L = tid & 63, s = tid >> 6;
    int cc = L & 15;
    int d0 = s * 32 + ((L >> 4) << 3);
    unsigned short h[8];
    float sq = 0.f;
    #pragma unroll
    for (int j = 0; j < 8; ++j) {
        float e = tile[(d0 + j) * 17 + cc];
        sq = fmaf(e, e, sq);
        h[j] = __half_as_ushort(__float2half(-2.f * e));
    }
    int T = b * 256 + tid;
    #pragma unroll
    for (int j = 0; j < 8; ++j) Ef[T * 8 + j] = h[j];
    atomicAdd(&e2s[cc], sq);
    __syncthreads();
    if (tid < 16) {
        e2[c0 + tid] = e2s[tid];
    }
}

// -------------------------------------------------------------------
// MFMA argmin. Measured-best config (R4): 3-buffer LDS ring (52 KB),
// stage-AFTER-compute into slot (q+2)%3 (WAR-safe via barrier(q) which
// all waves cross only after compute(q-1)); counted vmcnt(2) keeps the
// next chunk's DMA in flight across barriers; bound (512,4) -> VGPR 64,
// no spill (R8 at cap-256 chose 72 and was slightly SLOWER: 57.7 vs 55.5).
// Keys: dist' = e2 - 2x.e + 96, clamped to [0.5, 508] so every key is in
// a binade < 512 (10-bit trunc ULP <= 0.03125); clamped outliers give
// d1=d2=d3 -> triple-flagged. Top-3 certifies:
//   d3-d1 >= M2: argmin in {i1,i2}; d2-d1 < M1 -> exact fp32 pair inline.
//   d3-d1 <  M2 (rare): full K rescan in k_fix.
__launch_bounds__(512, 4)
__global__ void k_argmin_mfma(const float* __restrict__ x, const unsigned short* __restrict__ Ef,
                              const float* __restrict__ e2,
                              int* __restrict__ code_i, float* __restrict__ code_f,
                              int* __restrict__ cnt, int* __restrict__ rcnt,
                              int* __restrict__ rlist, const float* __restrict__ Et) {
    __shared__ unsigned short Bs[3][8192];   // 3 x 16 KB chunk ring
    __shared__ float e2s[K_];
    int tid = threadIdx.x;
    int w = tid >> 6, L = tid & 63, quad = L >> 4, col = L & 15;
    int mg = w >> 1, ng = w & 1;             // mg 0..3 (32-token groups), ng 0..1 (code half)
    int n0 = blockIdx.x * 128;

    for (int i = tid; i < K_; i += 512) e2s[i] = e2[i];

    // ---- A fragments (32 tokens/wave, fp16) ----
    half8 ah[2][4];
    #pragma unroll
    for (int mt = 0; mt < 2; ++mt) {
        int tok = n0 + (2 * mg + mt) * 16 + col;
        #pragma unroll
        for (int s = 0; s < 4; ++s) {
            const float* p = x + (size_t)tok * D_ + s * 32 + quad * 8;
            float4 u0 = *(const float4*)(p);
            float4 u1 = *(const float4*)(p + 4);
            ah[mt][s][0] = (_Float16)u0.x; ah[mt][s][1] = (_Float16)u0.y;
            ah[mt][s][2] = (_Float16)u0.z; ah[mt][s][3] = (_Float16)u0.w;
            ah[mt][s][4] = (_Float16)u1.x; ah[mt][s][5] = (_Float16)u1.y;
            ah[mt][s][6] = (_Float16)u1.z; ah[mt][s][7] = (_Float16)u1.w;
        }
    }

    unsigned k1[2][4], k2[2][4], k3[2][4];
    #pragma unroll
    for (int mt = 0; mt < 2; ++mt)
        #pragma unroll
        for (int r = 0; r < 4; ++r) {
            k1[mt][r] = 0xFFFFFFFFu; k2[mt][r] = 0xFFFFFFFFu; k3[mt][r] = 0xFFFFFFFFu;
        }

    __syncthreads();                          // e2s visible; nothing else in flight

    // ---- prologue: stage chunks 0,1 into slots 0,1 (2 ops each/wave) ----
    #pragma unroll
    for (int i = 0; i < 2; ++i) {
        int o = (w * 2 + i) * 512;
        gld16(Ef + o + L * 8, &Bs[0][o]);
    }
    #pragma unroll
    for (int i = 0; i < 2; ++i) {
        int o = (w * 2 + i) * 512;
        gld16(Ef + 8192 + o + L * 8, &Bs[1][o]);
    }

    #pragma unroll
    for (int q = 0; q < 16; ++q) {
        // outstanding here: chunk q (2 ops) + chunk q+1 (2 ops).
        // vmcnt(2) retires MY chunk-q loads; barrier => ALL waves' retired.
        if (q < 15) asm volatile("s_waitcnt vmcnt(2)" ::: "memory");
        else        asm volatile("s_waitcnt vmcnt(0)" ::: "memory");
        __builtin_amdgcn_s_barrier();
        asm volatile("" ::: "memory");

        const unsigned short* Bp = &Bs[q % 3][0];

        // ---- acc init = e2[code] + BIAS ----
        float evb[2];
        #pragma unroll
        for (int nn = 0; nn < 2; ++nn)
            evb[nn] = e2s[q * 64 + (2 * ng + nn) * 16 + col] + BIAS_;
        f32x4 acc[2][2];
        #pragma unroll
        for (int mt = 0; mt < 2; ++mt)
            #pragma unroll
            for (int nn = 0; nn < 2; ++nn)
                #pragma unroll
                for (int r = 0; r < 4; ++r)
                    acc[mt][nn][r] = evb[nn];

        // ---- 16 MFMA: 4 k-steps x 2 n-subs x 2 m-tiles ----
        #pragma unroll
        for (int s = 0; s < 4; ++s) {
            half8 bh[2];
            #pragma unroll
            for (int nn = 0; nn < 2; ++nn) {
                int off = (((2 * ng + nn) * 4 + s) * 64 + L) * 8;
                bh[nn] = *(const half8*)(Bp + off);
            }
            #pragma unroll
            for (int nn = 0; nn < 2; ++nn)
                #pragma unroll
                for (int mt = 0; mt < 2; ++mt)
                    acc[mt][nn] = __builtin_amdgcn_mfma_f32_16x16x32_f16(ah[mt][s], bh[nn], acc[mt][nn], 0, 0, 0);
        }

        // ---- clamp to [0.5,508] + packed-key top-3 insert ----
        #pragma unroll
        for (int nn = 0; nn < 2; ++nn) {
            unsigned cb = (unsigned)(q * 64 + (2 * ng + nn) * 16 + col);
            #pragma unroll
            for (int mt = 0; mt < 2; ++mt)
                #pragma unroll
                for (int r = 0; r < 4; ++r) {
                    float dc = fminf(fmaxf(acc[mt][nn][r], CLMIN_), CLMAX_);
                    unsigned key = (__float_as_uint(dc) & 0xFFFFFC00u) | cb;
                    unsigned m1 = umax32(k1[mt][r], key);
                    k1[mt][r]   = umin32(k1[mt][r], key);
                    unsigned m2 = umax32(k2[mt][r], m1);
                    k2[mt][r]   = umin32(k2[mt][r], m1);
                    k3[mt][r]   = umin32(k3[mt][r], m2);
                }
        }

        // ---- stage chunk q+2 into slot (q+2)%3 ----
        if (q < 14) {
            const unsigned short* src = Ef + (q + 2) * 8192;
            int sl = (q + 2) % 3;
            #pragma unroll
            for (int i = 0; i < 2; ++i) {
                int o = (w * 2 + i) * 512;
                gld16(src + o + L * 8, &Bs[sl][o]);
            }
        }
    }

    // ---- cross-lane merge of sorted triples over 16 cols ----
    __syncthreads();
    unsigned* mk1 = (unsigned*)&Bs[0][0];     // [128 tokens][2 halves] x 3
    unsigned* mk2 = mk1 + 256;
    unsigned* mk3 = mk2 + 256;

    #pragma unroll
    for (int mt = 0; mt < 2; ++mt) {
        #pragma unroll
        for (int r = 0; r < 4; ++r) {
            unsigned a = k1[mt][r], b = k2[mt][r], c = k3[mt][r];
            #pragma unroll
            for (int m = 1; m < 16; m <<= 1) {
                unsigned ao = (unsigned)__shfl_xor((int)a, m);
                unsigned bo = (unsigned)__shfl_xor((int)b, m);
                unsigned co = (unsigned)__shfl_xor((int)c, m);
                unsigned t1 = umax32(a, ao);
                a           = umin32(a, ao);
                unsigned s2 = umin32(b, bo);
                unsigned u  = umax32(t1, s2);
                b           = umin32(t1, s2);
                c           = umin32(u, umin32(c, co));
            }
            if (col == 0) {
                int tl = (2 * mg + mt) * 16 + quad * 4 + r;
                mk1[tl * 2 + ng] = a;
                mk2[tl * 2 + ng] = b;
                mk3[tl * 2 + ng] = c;
            }
        }
    }
    __syncthreads();
    if (tid < 128) {
        unsigned a1 = mk1[tid * 2], b1 = mk1[tid * 2 + 1];
        unsigned a2 = mk2[tid * 2], b2 = mk2[tid * 2 + 1];
        unsigned a3 = mk3[tid * 2], b3 = mk3[tid * 2 + 1];
        unsigned t1 = umax32(a1, b1);
        unsigned kk1 = umin32(a1, b1);
        unsigned s2 = umin32(a2, b2);
        unsigned kk2 = umin32(t1, s2);
        unsigned u  = umax32(t1, s2);
        unsigned kk3 = umin32(u, umin32(a3, b3));

        int i1 = (int)(kk1 & 1023u), i2 = (int)(kk2 & 1023u);
        float d1 = __uint_as_float(kk1 & 0xFFFFFC00u);
        float d2 = __uint_as_float(kk2 & 0xFFFFFC00u);
        float d3 = __uint_as_float(kk3 & 0xFFFFFC00u);
        int tok = n0 + tid;

        if (d3 - d1 < M2_) {
            // 3+ codes inside the uncertainty band: full exact rescan later
            code_i[tok] = i1;
            code_f[tok] = (float)i1;
            atomicAdd(cnt + i1, 1);
            int p = atomicAdd(rcnt, 1);
            rlist[p] = tok;
        } else {
            int win = i1;
            if (d2 - d1 < M1_) {
                // exact fp32 pair decision, inline (true argmin is i1 or i2)
                const float* xr = x  + (size_t)tok * D_;
                const float* ea = Et + (size_t)i1 * D_;
                const float* eb = Et + (size_t)i2 * D_;
                float s1 = 0.f, sB = 0.f;
                #pragma unroll 4
                for (int dd = 0; dd < D_; dd += 4) {
                    float4 xv = *(const float4*)(xr + dd);
                    float4 av = *(const float4*)(ea + dd);
                    float4 bv = *(const float4*)(eb + dd);
                    s1 = fmaf(xv.x, av.x, s1); s1 = fmaf(xv.y, av.y, s1);
                    s1 = fmaf(xv.z, av.z, s1); s1 = fmaf(xv.w, av.w, s1);
                    sB = fmaf(xv.x, bv.x, sB); sB = fmaf(xv.y, bv.y, sB);
                    sB = fmaf(xv.z, bv.z, sB); sB = fmaf(xv.w, bv.w, sB);
                }
                float ex1 = e2s[i1] - 2.f * s1;
                float ex2 = e2s[i2] - 2.f * sB;
                if (ex2 < ex1 || (ex2 == ex1 && i2 < i1)) win = i2;
            }
            code_i[tok] = win;
            code_f[tok] = (float)win;
            atomicAdd(cnt + win, 1);
        }
    }
}

// -------------------------------------------------------------------
// exact fp32 re-argmin for triple-ambiguous tokens (rare)
__launch_bounds__(256)
__global__ void k_fix(const float* __restrict__ x, const float* __restrict__ Et,
                      const float* __restrict__ e2, const int* __restrict__ rcnt,
                      const int* __restrict__ rlist, int* __restrict__ code_i,
                      float* __restrict__ code_f, int* __restrict__ cnt) {
    __shared__ float4 xs[32];
    __shared__ float sd[8];
    __shared__ int   si[8];
    int tid = threadIdx.x;
    int lane = tid & 63, w = tid >> 6;
    int half = lane >> 5;
    int q32  = lane & 31;
    int slot = w * 2 + half;     // 0..7: codes c ≡ slot (mod 8)
    int nr = *rcnt;
    for (int it = blockIdx.x; it < nr; it += gridDim.x) {
        __syncthreads();
        int tok = rlist[it];
        if (tid < 32) xs[tid] = ((const float4*)(x + (size_t)tok * D_))[tid];
        __syncthreads();
        float4 xv = xs[q32];
        float bd = INFINITY; int bb = 0;
        for (int c0 = 0; c0 < K_; c0 += 8) {
            int c = c0 + slot;
            float4 e = ((const float4*)(Et + (size_t)c * D_))[q32];
            float dot = xv.x * e.x + xv.y * e.y + xv.z * e.z + xv.w * e.w;
            dot += __shfl_xor(dot, 1);
            dot += __shfl_xor(dot, 2);
            dot += __shfl_xor(dot, 4);
            dot += __shfl_xor(dot, 8);
            dot += __shfl_xor(dot, 16);
            float dist = e2[c] - 2.f * dot;
            if (dist < bd) { bd = dist; bb = c; }   // c ascending => first-min
        }
        if (q32 == 0) { sd[slot] = bd; si[slot] = bb; }
        __syncthreads();
        if (tid == 0) {
            float fb = sd[0]; int fi = si[0];
            #pragma unroll
            for (int s = 1; s < 8; ++s) {
                if (sd[s] < fb || (sd[s] == fb && si[s] < fi)) { fb = sd[s]; fi = si[s]; }
            }
            int ob = code_i[tok];
            if (fi != ob) {
                code_i[tok] = fi;
                code_f[tok] = (float)fi;
                atomicAdd(cnt + ob, -1);
                atomicAdd(cnt + fi, 1);
            }
        }
    }
}

// -------------------------------------------------------------------
// Cooperative tail: ONE launch replaces k_scan + k_scatter + k_segdeq +
// k_embed (each small kernel costs ~10-25 us of launch+run wall time;
// the k_post ledger R7->R8 measured 23 us for a trivial kernel).
// Grid 2048 x 128 (8 blk/CU, 16 waves/CU, ~5 KB LDS -> co-resident).
// Phase 1: redundant per-block exclusive scan of cnt (LDS) + scatter
//          (blocks < 512) via base[c] + atomicAdd(zc+c).
// Phase 2: uniform-slice segdeq (identical logic to R8's k_segdeq).
// Phase 3: embed (identical math to R8's k_embed).
__launch_bounds__(128)
__global__ void k_coop(const int* __restrict__ cnt, int* __restrict__ zc,
                       const int* __restrict__ code_i, int* __restrict__ order,
                       int* __restrict__ csort, const float* __restrict__ x,
                       const float* __restrict__ Et, float* __restrict__ part1,
                       float* __restrict__ outq, float* __restrict__ ssqp,
                       const float* __restrict__ em, const float* __restrict__ csz,
                       float* __restrict__ out_nmean, float* __restrict__ out_nemb,
                       float* __restrict__ out_ncs, float* __restrict__ out_diff) {
    cg::grid_group grid = cg::this_grid();
    __shared__ int baseS[1025];
    __shared__ int sn[WSEG], sc[WSEG];
    __shared__ float red[128];
    int tid = threadIdx.x;
    int bid = blockIdx.x;
    int lane = tid & 63, wv = tid >> 6;

    // ---- phase 1a: exclusive scan of cnt[1024] (redundant per block) ----
    int c8[8];
    #pragma unroll
    for (int j = 0; j < 8; ++j) c8[j] = cnt[8 * tid + j];
    int s = 0;
    #pragma unroll
    for (int j = 0; j < 8; ++j) s += c8[j];
    int ps = s;
    #pragma unroll
    for (int m = 1; m < 64; m <<= 1) {
        int o = __shfl_up(ps, m);
        if (lane >= m) ps += o;
    }
    __shared__ int wtot[2];
    if (lane == 63) wtot[wv] = ps;
    __syncthreads();
    int woff = (wv == 1) ? wtot[0] : 0;
    int run = woff + ps - s;
    #pragma unroll
    for (int j = 0; j < 8; ++j) {
        run += c8[j];
        baseS[8 * tid + j + 1] = run;
    }
    if (tid == 0) baseS[0] = 0;
    __syncthreads();

    // ---- phase 1b: scatter (blocks 0..511, 128 tokens each) ----
    if (bid < 512) {
        int n = bid * 128 + tid;
        int c = code_i[n];
        int pos = baseS[c] + atomicAdd(zc + c, 1);
        order[pos] = n;
        csort[pos] = c;
    }
    grid.sync();

    // ---- phase 2: uniform-slice segment-sum + dequant/ST/ssq ----
    {
        int d = tid;
        int i0 = bid * WSEG;
        if (d < WSEG) { sn[d] = order[i0 + d]; sc[d] = csort[i0 + d]; }
        __syncthreads();
        int cprev = sc[0];
        float eq = Et[(size_t)cprev * D_ + d];
        float acc = 0.f, ssql = 0.f;
        float xv = x[(size_t)sn[0] * D_ + d];
        #pragma unroll 4
        for (int j = 0; j < WSEG; ++j) {
            float xn = (j < WSEG - 1) ? x[(size_t)sn[j + 1] * D_ + d] : 0.f;  // prefetch
            int c = sc[j];
            if (c != cprev) {                      // wave-uniform branch
                atomicAdd(&part1[(size_t)cprev * D_ + d], acc);
                acc = 0.f;
                eq = Et[(size_t)c * D_ + d];
                cprev = c;
            }
            float qv = xv + (eq - xv);             // reference fp32 rounding
            outq[(size_t)sn[j] * D_ + d] = qv;
            float t = qv - xv;
            ssql = fmaf(t, t, ssql);
            acc += xv;
            xv = xn;
        }
        atomicAdd(&part1[(size_t)cprev * D_ + d], acc);

        #pragma unroll
        for (int off = 32; off > 0; off >>= 1) ssql += __shfl_down(ssql, off);
        __shared__ float wsum[2];
        if ((d & 63) == 0) wsum[d >> 6] = ssql;
        __syncthreads();
        if (d == 0) atomicAdd(ssqp, wsum[0] + wsum[1]);
    }
    grid.sync();

    // ---- phase 3: stats + embed ----
    {
        float ls = 0.f;
        for (int j = tid; j < K_; j += 128) ls += csz[j] * DECAY_ + OMD_ * (float)cnt[j];
        red[tid] = ls;
        __syncthreads();
        for (int off = 64; off > 0; off >>= 1) {
            if (tid < off) red[tid] += red[tid + off];
            __syncthreads();
        }
        float n = red[0];

        if (bid == 0) {
            for (int j = tid; j < K_; j += 128)
                out_ncs[j] = csz[j] * DECAY_ + OMD_ * (float)cnt[j];
            if (tid == 0) *out_diff = VQC_ * ssqp[0] / (float)(N_ * D_);
        }

        if (bid < 1024) {
            int i = bid * 128 + tid;              // over D*K, layout [D][K]
            int k = i & (K_ - 1);
            int d = i >> 10;
            float ncs_k = csz[k] * DECAY_ + OMD_ * (float)cnt[k];
            float csk = (ncs_k + EPS_) / (n + (float)K_ * EPS_) * n;
            float es = part1[(size_t)k * D_ + d];
            float nm = em[i] * DECAY_ + OMD_ * es;
            out_nmean[i] = nm;
            out_nemb[i]  = nm / csk;
        }
    }
}

// -------------------------------------------------------------------
extern "C" void kernel_launch(void* const* d_in, const int* in_sizes, int n_in,
                              void* d_out, int out_size, void* d_ws, size_t ws_size,
                              hipStream_t stream) {
    const float* x   = (const float*)d_in[0];   // [16,4096,128]
    const float* E   = (const float*)d_in[1];   // [128,1024]
    const float* csz = (const float*)d_in[2];   // [1024]
    const float* em  = (const float*)d_in[3];   // [128,1024]
    float* out = (float*)d_out;
    float* W   = (float*)d_ws;

    int*   code_i = (int*)(W + WOFF_CODE);
    float* e2     = W + WOFF_E2;
    int*   cnt    = (int*)(W + WOFF_CNT);
    float* ssqp   = W + WOFF_SSQ;
    int*   rcnt   = (int*)(W + WOFF_RCNT);
    int*   zc     = (int*)(W + WOFF_CURS);
    int*   order  = (int*)(W + WOFF_ORDER);
    float* Et     = W + WOFF_ET;
    float* part1  = W + WOFF_PART;
    int*   csort  = (int*)(W + WOFF_CSORT);
    int*   rlist  = (int*)(W + WOFF_RLIST);
    unsigned short* Ef = (unsigned short*)(W + WOFF_EF);

    float* code_o = out + OOFF_CODE;
    float* outq   = out + OOFF_Q;
    float* nmean  = out + OOFF_NMEAN;
    float* nemb   = out + OOFF_NEMB;
    float* ncs    = out + OOFF_NCS;
    float* diffp  = out + OOFF_DIFF;

    k_prep<<<64, 256, 0, stream>>>(E, Et, Ef, e2, cnt, zc, part1);
    k_argmin_mfma<<<N_ / 128, 512, 0, stream>>>(x, Ef, e2, code_i, code_o,
                                                cnt, rcnt, rlist, Et);
    k_fix<<<1024, 256, 0, stream>>>(x, Et, e2, rcnt, rlist, code_i, code_o, cnt);

    void* args[] = { &cnt, &zc, &code_i, &order, &csort, &x, &Et, &part1,
                     &outq, &ssqp, &em, &csz, &nmean, &nemb, &ncs, &diffp };
    hipLaunchCooperativeKernel((void*)k_coop, dim3(CBLK), dim3(128), args, 0, stream);
}

// Round 10
// 248.651 us; speedup vs baseline: 2.2383x; 2.2383x over previous
//
#include <hip/hip_runtime.h>
#include <hip/hip_fp16.h>
#include <math.h>

#define D_ 128
#define K_ 1024
#define N_ 65536
#define DECAY_ 0.99f
#define OMD_ 0.01f
#define EPS_ 1e-5f
#define VQC_ 0.25f
#define M1_ 0.14f     // pair band: 2*eps(fp16 dot) + 2*keytrunc
#define M2_ 0.14f     // triple band -> full K rescan
#define BIAS_ 96.0f   // positivity shift for e2-2xe (argmin-invariant per token)
#define CLMIN_ 0.5f
#define CLMAX_ 508.0f // keys < 512 => trunc ULP 2^-5; clamped => triple-flagged
#define WSEG 32       // tokens per k_segdeq block (uniform work)

typedef __attribute__((ext_vector_type(8))) _Float16 half8;
typedef __attribute__((ext_vector_type(4))) float f32x4;

// ---- workspace offsets (in 4-byte elements) ----
#define WOFF_CODE  0          // int[65536]
#define WOFF_E2    65536      // float[1024]
#define WOFF_CNT   66560      // int[1024]
#define WOFF_SSQ   67584      // float[1]  (zeroed by k_prep block 0)
#define WOFF_RCNT  67585      // int[1]    (CNT..RCNT zeroed by k_prep block 0)
#define WOFF_BASE  67648      // int[1025]
#define WOFF_CURS  68736      // int[1024]
#define WOFF_ORDER 69760      // int[65536]
#define WOFF_ET    136320     // float[131072] (K x D), 16B aligned
#define WOFF_PART  267392     // float[131072] (K x D) atomic segment sums
#define WOFF_CSORT 398464     // int[65536] code of each sorted slot
#define WOFF_RLIST 791680     // int[65536]
#define WOFF_EF    857216     // ushort[131072] frag-ordered fp16 of -2E

// ---- output offsets (in floats), reference return order ----
#define OOFF_Q     0          // [16,4096,128]
#define OOFF_DIFF  8388608    // scalar
#define OOFF_CODE  8388609    // [16,4096]
#define OOFF_NEMB  8454145    // [128,1024]
#define OOFF_NCS   8585217    // [1024]
#define OOFF_NMEAN 8586241    // [128,1024]

__device__ __forceinline__ unsigned umin32(unsigned a, unsigned b) { return a < b ? a : b; }
__device__ __forceinline__ unsigned umax32(unsigned a, unsigned b) { return a > b ? a : b; }

// -------------------------------------------------------------------
// Fused prep: E [D][K] -> Et [K][D], fp16 frag plane Ef of -2E, e2,
// cnt/ssq/rcnt zeroing (block 0), and part1 zeroing (all blocks).
__launch_bounds__(256)
__global__ void k_prep(const float* __restrict__ E, float* __restrict__ Et,
                       unsigned short* __restrict__ Ef, float* __restrict__ e2,
                       int* __restrict__ cnt, float* __restrict__ part1) {
    __shared__ float tile[128 * 17];   // tile[d][cc], pad 17 vs 16
    __shared__ float e2s[16];
    int tid = threadIdx.x;
    int b = blockIdx.x;                // 0..63
    int c0 = b * 16;
    if (b == 0) {
        for (int i = tid; i < 1026; i += 256) cnt[i] = 0;   // cnt[1024], ssq, rcnt
    }
    // zero part1 (K*D floats, 2048 per block)
    #pragma unroll
    for (int i = 0; i < 8; ++i) part1[b * 2048 + i * 256 + tid] = 0.f;
    if (tid < 16) e2s[tid] = 0.f;
    // ---- load E columns c0..c0+15 (2048 floats) ----
    #pragma unroll
    for (int i = 0; i < 8; ++i) {
        int idx = i * 256 + tid;       // 0..2047
        int d = idx >> 4, cc = idx & 15;
        tile[d * 17 + cc] = E[d * K_ + c0 + cc];
    }
    __syncthreads();
    // ---- write Et rows (coalesced, conflict-free via pad) ----
    #pragma unroll
    for (int i = 0; i < 8; ++i) {
        int idx = i * 256 + tid;
        int cc = idx >> 7, d = idx & 127;
        Et[(size_t)(c0 + cc) * D_ + d] = tile[d * 17 + cc];
    }
    // ---- Ef frags + e2 ----
    int L = tid & 63, s = tid >> 6;
    int cc = L & 15;
    int d0 = s * 32 + ((L >> 4) << 3);
    unsigned short h[8];
    float sq = 0.f;
    #pragma unroll
    for (int j = 0; j < 8; ++j) {
        float e = tile[(d0 + j) * 17 + cc];
        sq = fmaf(e, e, sq);
        h[j] = __half_as_ushort(__float2half(-2.f * e));
    }
    int T = b * 256 + tid;
    #pragma unroll
    for (int j = 0; j < 8; ++j) Ef[T * 8 + j] = h[j];
    atomicAdd(&e2s[cc], sq);
    __syncthreads();
    if (tid < 16) {
        e2[c0 + tid] = e2s[tid];
    }
}

// -------------------------------------------------------------------
// MFMA argmin, BARRIER-FREE: each wave owns 32 tokens and streams ALL
// 1024 codes' B-frags directly from Ef via coalesced 1KB global loads
// (codebook = 256KB, L2-resident per XCD; 2048 waves x 256KB = 512MB of
// L2 traffic ~ 15us at 34.5 TB/s). No LDS staging, no s_barrier in the
// main loop -- removes the 8-wave convoy stall that kept every LDS-ring
// variant at ~60% dead cycles (R4/R7/R8: MfmaUtil 11%, VALU 29%,
// occupancy <28%). ILP: 8 independent MFMA chains + 16 loads in flight.
// Byte-layout equivalence with the proven LDS path: producer index
// (4q+g)*2048+s*512+L*8 == consumer q*8192+g*2048+s*512+L*8.
// Keys: dist' = e2 - 2x.e + 96, clamped to [0.5,508] (binade < 512 ->
// 10-bit trunc ULP <= 0.03125; clamped outliers => d1=d2=d3 => flagged).
// Top-3 certifies: d3-d1 >= M2: argmin in {i1,i2}; d2-d1 < M1 -> exact
// fp32 pair inline. d3-d1 < M2 (rare): full K rescan in k_fix.
__launch_bounds__(256)
__global__ void k_argmin_mfma(const float* __restrict__ x, const unsigned short* __restrict__ Ef,
                              const float* __restrict__ e2,
                              int* __restrict__ code_i, float* __restrict__ code_f,
                              int* __restrict__ cnt, int* __restrict__ rcnt,
                              int* __restrict__ rlist, const float* __restrict__ Et) {
    __shared__ float e2s[K_];            // 4 KB
    __shared__ unsigned mk1[128], mk2[128], mk3[128];   // 1.5 KB triples
    int tid = threadIdx.x;
    int w = tid >> 6, L = tid & 63, quad = L >> 4, col = L & 15;
    int n0 = blockIdx.x * 128 + w * 32;  // this wave's 32 tokens

    for (int i = tid; i < K_; i += 256) e2s[i] = e2[i];

    // ---- A fragments (32 tokens/wave, fp16) ----
    half8 ah[2][4];
    #pragma unroll
    for (int mt = 0; mt < 2; ++mt) {
        int tok = n0 + mt * 16 + col;
        #pragma unroll
        for (int s = 0; s < 4; ++s) {
            const float* p = x + (size_t)tok * D_ + s * 32 + quad * 8;
            float4 u0 = *(const float4*)(p);
            float4 u1 = *(const float4*)(p + 4);
            ah[mt][s][0] = (_Float16)u0.x; ah[mt][s][1] = (_Float16)u0.y;
            ah[mt][s][2] = (_Float16)u0.z; ah[mt][s][3] = (_Float16)u0.w;
            ah[mt][s][4] = (_Float16)u1.x; ah[mt][s][5] = (_Float16)u1.y;
            ah[mt][s][6] = (_Float16)u1.z; ah[mt][s][7] = (_Float16)u1.w;
        }
    }

    unsigned k1[2][4], k2[2][4], k3[2][4];
    #pragma unroll
    for (int mt = 0; mt < 2; ++mt)
        #pragma unroll
        for (int r = 0; r < 4; ++r) {
            k1[mt][r] = 0xFFFFFFFFu; k2[mt][r] = 0xFFFFFFFFu; k3[mt][r] = 0xFFFFFFFFu;
        }

    __syncthreads();                     // e2s ready (only barrier before epilogue)

    #pragma unroll 2
    for (int q = 0; q < 16; ++q) {
        const unsigned short* Bq = Ef + (size_t)q * 8192;

        // ---- acc init = e2[code] + BIAS (4 code-16-groups per chunk) ----
        f32x4 acc[2][4];
        #pragma unroll
        for (int g = 0; g < 4; ++g) {
            float ev = e2s[q * 64 + g * 16 + col] + BIAS_;
            acc[0][g] = (f32x4){ev, ev, ev, ev};
            acc[1][g] = (f32x4){ev, ev, ev, ev};
        }

        // ---- 32 MFMA: 4 k-steps x 4 code-groups x 2 m-tiles ----
        #pragma unroll
        for (int s = 0; s < 4; ++s) {
            half8 bh[4];
            #pragma unroll
            for (int g = 0; g < 4; ++g)
                bh[g] = *(const half8*)(Bq + ((g * 4 + s) * 64 + L) * 8);
            #pragma unroll
            for (int g = 0; g < 4; ++g) {
                acc[0][g] = __builtin_amdgcn_mfma_f32_16x16x32_f16(ah[0][s], bh[g], acc[0][g], 0, 0, 0);
                acc[1][g] = __builtin_amdgcn_mfma_f32_16x16x32_f16(ah[1][s], bh[g], acc[1][g], 0, 0, 0);
            }
        }

        // ---- clamp (v_med3) + packed-key top-3 sorted-insert ----
        #pragma unroll
        for (int g = 0; g < 4; ++g) {
            unsigned cb = (unsigned)(q * 64 + g * 16 + col);
            #pragma unroll
            for (int mt = 0; mt < 2; ++mt)
                #pragma unroll
                for (int r = 0; r < 4; ++r) {
                    float dc = fminf(fmaxf(acc[mt][g][r], CLMIN_), CLMAX_);
                    unsigned key = (__float_as_uint(dc) & 0xFFFFFC00u) | cb;
                    unsigned m1 = umax32(k1[mt][r], key);
                    k1[mt][r]   = umin32(k1[mt][r], key);
                    unsigned m2 = umax32(k2[mt][r], m1);
                    k2[mt][r]   = umin32(k2[mt][r], m1);
                    k3[mt][r]   = umin32(k3[mt][r], m2);
                }
        }
    }

    // ---- within-wave butterfly over 16 cols; triples to LDS ----
    #pragma unroll
    for (int mt = 0; mt < 2; ++mt) {
        #pragma unroll
        for (int r = 0; r < 4; ++r) {
            unsigned a = k1[mt][r], b = k2[mt][r], c = k3[mt][r];
            #pragma unroll
            for (int m = 1; m < 16; m <<= 1) {
                unsigned ao = (unsigned)__shfl_xor((int)a, m);
                unsigned bo = (unsigned)__shfl_xor((int)b, m);
                unsigned co = (unsigned)__shfl_xor((int)c, m);
                unsigned t1 = umax32(a, ao);
                a           = umin32(a, ao);
                unsigned s2 = umin32(b, bo);
                unsigned u  = umax32(t1, s2);
                b           = umin32(t1, s2);
                c           = umin32(u, umin32(c, co));
            }
            if (col == 0) {
                int tl = w * 32 + mt * 16 + quad * 4 + r;
                mk1[tl] = a;
                mk2[tl] = b;
                mk3[tl] = c;
            }
        }
    }
    __syncthreads();
    if (tid < 128) {
        unsigned kk1 = mk1[tid], kk2 = mk2[tid], kk3 = mk3[tid];
        int i1 = (int)(kk1 & 1023u), i2 = (int)(kk2 & 1023u);
        float d1 = __uint_as_float(kk1 & 0xFFFFFC00u);
        float d2 = __uint_as_float(kk2 & 0xFFFFFC00u);
        float d3 = __uint_as_float(kk3 & 0xFFFFFC00u);
        int tok = blockIdx.x * 128 + tid;

        if (d3 - d1 < M2_) {
            // 3+ codes inside the uncertainty band: full exact rescan later
            code_i[tok] = i1;
            code_f[tok] = (float)i1;
            atomicAdd(cnt + i1, 1);
            int p = atomicAdd(rcnt, 1);
            rlist[p] = tok;
        } else {
            int win = i1;
            if (d2 - d1 < M1_) {
                // exact fp32 pair decision, inline (true argmin is i1 or i2)
                const float* xr = x  + (size_t)tok * D_;
                const float* ea = Et + (size_t)i1 * D_;
                const float* eb = Et + (size_t)i2 * D_;
                float s1 = 0.f, sB = 0.f;
                #pragma unroll 4
                for (int dd = 0; dd < D_; dd += 4) {
                    float4 xv = *(const float4*)(xr + dd);
                    float4 av = *(const float4*)(ea + dd);
                    float4 bv = *(const float4*)(eb + dd);
                    s1 = fmaf(xv.x, av.x, s1); s1 = fmaf(xv.y, av.y, s1);
                    s1 = fmaf(xv.z, av.z, s1); s1 = fmaf(xv.w, av.w, s1);
                    sB = fmaf(xv.x, bv.x, sB); sB = fmaf(xv.y, bv.y, sB);
                    sB = fmaf(xv.z, bv.z, sB); sB = fmaf(xv.w, bv.w, sB);
                }
                float ex1 = e2s[i1] - 2.f * s1;
                float ex2 = e2s[i2] - 2.f * sB;
                if (ex2 < ex1 || (ex2 == ex1 && i2 < i1)) win = i2;
            }
            code_i[tok] = win;
            code_f[tok] = (float)win;
            atomicAdd(cnt + win, 1);
        }
    }
}

// -------------------------------------------------------------------
// exact fp32 re-argmin for triple-ambiguous tokens (rare)
__launch_bounds__(256)
__global__ void k_fix(const float* __restrict__ x, const float* __restrict__ Et,
                      const float* __restrict__ e2, const int* __restrict__ rcnt,
                      const int* __restrict__ rlist, int* __restrict__ code_i,
                      float* __restrict__ code_f, int* __restrict__ cnt) {
    __shared__ float4 xs[32];
    __shared__ float sd[8];
    __shared__ int   si[8];
    int tid = threadIdx.x;
    int lane = tid & 63, w = tid >> 6;
    int half = lane >> 5;
    int q32  = lane & 31;
    int slot = w * 2 + half;     // 0..7: codes c ≡ slot (mod 8)
    int nr = *rcnt;
    for (int it = blockIdx.x; it < nr; it += gridDim.x) {
        __syncthreads();
        int tok = rlist[it];
        if (tid < 32) xs[tid] = ((const float4*)(x + (size_t)tok * D_))[tid];
        __syncthreads();
        float4 xv = xs[q32];
        float bd = INFINITY; int bb = 0;
        for (int c0 = 0; c0 < K_; c0 += 8) {
            int c = c0 + slot;
            float4 e = ((const float4*)(Et + (size_t)c * D_))[q32];
            float dot = xv.x * e.x + xv.y * e.y + xv.z * e.z + xv.w * e.w;
            dot += __shfl_xor(dot, 1);
            dot += __shfl_xor(dot, 2);
            dot += __shfl_xor(dot, 4);
            dot += __shfl_xor(dot, 8);
            dot += __shfl_xor(dot, 16);
            float dist = e2[c] - 2.f * dot;
            if (dist < bd) { bd = dist; bb = c; }   // c ascending => first-min
        }
        if (q32 == 0) { sd[slot] = bd; si[slot] = bb; }
        __syncthreads();
        if (tid == 0) {
            float fb = sd[0]; int fi = si[0];
            #pragma unroll
            for (int s = 1; s < 8; ++s) {
                if (sd[s] < fb || (sd[s] == fb && si[s] < fi)) { fb = sd[s]; fi = si[s]; }
            }
            int ob = code_i[tok];
            if (fi != ob) {
                code_i[tok] = fi;
                code_f[tok] = (float)fi;
                atomicAdd(cnt + ob, -1);
                atomicAdd(cnt + fi, 1);
            }
        }
    }
}

// -------------------------------------------------------------------
// exclusive scan of code histogram -> base, cursor (256 thr, shfl scan)
__launch_bounds__(256)
__global__ void k_scan(const int* __restrict__ cnt, int* __restrict__ base,
                       int* __restrict__ cursor) {
    int t = threadIdx.x;
    int lane = t & 63, wv = t >> 6;
    int c[4];
    #pragma unroll
    for (int j = 0; j < 4; ++j) c[j] = cnt[4 * t + j];
    int s = c[0] + c[1] + c[2] + c[3];
    int ps = s;
    #pragma unroll
    for (int m = 1; m < 64; m <<= 1) {
        int o = __shfl_up(ps, m);
        if (lane >= m) ps += o;
    }
    __shared__ int wtot[4];
    if (lane == 63) wtot[wv] = ps;
    __syncthreads();
    int woff = 0;
    for (int i = 0; i < 4; ++i) if (i < wv) woff += wtot[i];
    int run = woff + ps - s;
    #pragma unroll
    for (int j = 0; j < 4; ++j) {
        cursor[4 * t + j] = run;
        run += c[j];
        base[4 * t + j + 1] = run;
    }
    if (t == 0) base[0] = 0;
}

// -------------------------------------------------------------------
// token-index scatter into code-sorted order list (+ code per slot)
__global__ void k_scatter(const int* __restrict__ code_i, int* __restrict__ cursor,
                          int* __restrict__ order, int* __restrict__ csort) {
    int n = blockIdx.x * 256 + threadIdx.x;
    int c = code_i[n];
    int pos = atomicAdd(cursor + c, 1);
    order[pos] = n;
    csort[pos] = c;
}

// -------------------------------------------------------------------
// UNIFORM-WORK fused segment-sum + dequant/ST/ssq: block i owns sorted
// slots [32i, 32i+32) — fixed 16KB read + 16KB write per block.
// Segment boundaries flush the running per-dim sum via one fp32
// atomicAdd into part1[c][d].
__launch_bounds__(128)
__global__ void k_segdeq(const float* __restrict__ x, const float* __restrict__ Et,
                         const int* __restrict__ order, const int* __restrict__ csort,
                         float* __restrict__ part1, float* __restrict__ outq,
                         float* __restrict__ ssqp) {
    __shared__ int sn[WSEG], sc[WSEG];
    int d = threadIdx.x;
    int i0 = blockIdx.x * WSEG;
    if (d < WSEG) { sn[d] = order[i0 + d]; sc[d] = csort[i0 + d]; }
    __syncthreads();
    int cprev = sc[0];
    float eq = Et[(size_t)cprev * D_ + d];
    float acc = 0.f, ssql = 0.f;
    float xv = x[(size_t)sn[0] * D_ + d];
    #pragma unroll 4
    for (int j = 0; j < WSEG; ++j) {
        float xn = (j < WSEG - 1) ? x[(size_t)sn[j + 1] * D_ + d] : 0.f;  // prefetch
        int c = sc[j];
        if (c != cprev) {                      // wave-uniform branch
            atomicAdd(&part1[(size_t)cprev * D_ + d], acc);
            acc = 0.f;
            eq = Et[(size_t)c * D_ + d];
            cprev = c;
        }
        float qv = xv + (eq - xv);             // reference fp32 rounding
        outq[(size_t)sn[j] * D_ + d] = qv;
        float t = qv - xv;
        ssql = fmaf(t, t, ssql);
        acc += xv;
        xv = xn;
    }
    atomicAdd(&part1[(size_t)cprev * D_ + d], acc);

    // block-reduce ssql (2 waves of 64) -> one global atomic
    #pragma unroll
    for (int off = 32; off > 0; off >>= 1) ssql += __shfl_down(ssql, off);
    __shared__ float wsum[2];
    if ((d & 63) == 0) wsum[d >> 6] = ssql;
    __syncthreads();
    if (d == 0) atomicAdd(ssqp, wsum[0] + wsum[1]);
}

// -------------------------------------------------------------------
// fused stats + embed: each block redundantly reduces n; block 0 also
// writes out_ncs + out_diff. Then EMA mean + divide for its 256 elems.
__launch_bounds__(256)
__global__ void k_embed(const float* __restrict__ em, const float* __restrict__ part1,
                        const int* __restrict__ cnt, const float* __restrict__ csz,
                        const float* __restrict__ ssqp, float* __restrict__ out_nmean,
                        float* __restrict__ out_nemb, float* __restrict__ out_ncs,
                        float* __restrict__ out_diff) {
    int tid = threadIdx.x;
    __shared__ float red[256];

    // ---- n = sum_k ncs_k (redundant per block) ----
    float ls = 0.f;
    for (int j = tid; j < K_; j += 256) ls += csz[j] * DECAY_ + OMD_ * (float)cnt[j];
    red[tid] = ls;
    __syncthreads();
    for (int off = 128; off > 0; off >>= 1) {
        if (tid < off) red[tid] += red[tid + off];
        __syncthreads();
    }
    float n = red[0];
    __syncthreads();

    if (blockIdx.x == 0) {
        for (int j = tid; j < K_; j += 256)
            out_ncs[j] = csz[j] * DECAY_ + OMD_ * (float)cnt[j];
        if (tid == 0) *out_diff = VQC_ * ssqp[0] / (float)(N_ * D_);
    }

    int i = blockIdx.x * 256 + tid;           // over D*K, layout [D][K]
    int k = i & (K_ - 1);
    int d = i >> 10;
    float ncs_k = csz[k] * DECAY_ + OMD_ * (float)cnt[k];
    float csk = (ncs_k + EPS_) / (n + (float)K_ * EPS_) * n;
    float es = part1[(size_t)k * D_ + d];
    float nm = em[i] * DECAY_ + OMD_ * es;
    out_nmean[i] = nm;
    out_nemb[i]  = nm / csk;
}

// -------------------------------------------------------------------
extern "C" void kernel_launch(void* const* d_in, const int* in_sizes, int n_in,
                              void* d_out, int out_size, void* d_ws, size_t ws_size,
                              hipStream_t stream) {
    const float* x   = (const float*)d_in[0];   // [16,4096,128]
    const float* E   = (const float*)d_in[1];   // [128,1024]
    const float* csz = (const float*)d_in[2];   // [1024]
    const float* em  = (const float*)d_in[3];   // [128,1024]
    float* out = (float*)d_out;
    float* W   = (float*)d_ws;

    int*   code_i = (int*)(W + WOFF_CODE);
    float* e2     = W + WOFF_E2;
    int*   cnt    = (int*)(W + WOFF_CNT);
    float* ssqp   = W + WOFF_SSQ;
    int*   rcnt   = (int*)(W + WOFF_RCNT);
    int*   base   = (int*)(W + WOFF_BASE);
    int*   cursor = (int*)(W + WOFF_CURS);
    int*   order  = (int*)(W + WOFF_ORDER);
    float* Et     = W + WOFF_ET;
    float* part1  = W + WOFF_PART;
    int*   csort  = (int*)(W + WOFF_CSORT);
    int*   rlist  = (int*)(W + WOFF_RLIST);
    unsigned short* Ef = (unsigned short*)(W + WOFF_EF);

    k_prep<<<64, 256, 0, stream>>>(E, Et, Ef, e2, cnt, part1);
    k_argmin_mfma<<<N_ / 128, 256, 0, stream>>>(x, Ef, e2, code_i,
                                                out + OOFF_CODE, cnt, rcnt, rlist, Et);
    k_fix<<<1024, 256, 0, stream>>>(x, Et, e2, rcnt, rlist, code_i, out + OOFF_CODE, cnt);
    k_scan<<<1, 256, 0, stream>>>(cnt, base, cursor);
    k_scatter<<<N_ / 256, 256, 0, stream>>>(code_i, cursor, order, csort);
    k_segdeq<<<N_ / WSEG, 128, 0, stream>>>(x, Et, order, csort, part1,
                                            out + OOFF_Q, ssqp);
    k_embed<<<(D_ * K_) / 256, 256, 0, stream>>>(em, part1, cnt, csz, ssqp,
                                                 out + OOFF_NMEAN, out + OOFF_NEMB,
                                                 out + OOFF_NCS, out + OOFF_DIFF);
}

// Round 11
// 233.901 us; speedup vs baseline: 2.3794x; 1.0631x over previous
//
#include <hip/hip_runtime.h>
#include <hip/hip_fp16.h>
#include <math.h>

#define D_ 128
#define K_ 1024
#define N_ 65536
#define DECAY_ 0.99f
#define OMD_ 0.01f
#define EPS_ 1e-5f
#define VQC_ 0.25f
#define M1_ 0.14f     // pair band: 2*eps(fp16 dot) + 2*keytrunc
#define M2_ 0.14f     // triple band -> full K rescan
#define BIAS_ 96.0f   // positivity shift for e2-2xe (argmin-invariant per token)
#define CLMIN_ 0.5f
#define CLMAX_ 508.0f // keys < 512 => trunc ULP 2^-5; clamped => triple-flagged
#define WSEG 32       // tokens per k_segdeq block (2 x 16-slot halves)

typedef __attribute__((ext_vector_type(8))) _Float16 half8;
typedef __attribute__((ext_vector_type(4))) float f32x4;

// ---- workspace offsets (in 4-byte elements) ----
#define WOFF_CODE  0          // int[65536]
#define WOFF_E2    65536      // float[1024]
#define WOFF_CNT   66560      // int[1024]
#define WOFF_SSQ   67584      // float[1]  (zeroed by k_prep block 0)
#define WOFF_RCNT  67585      // int[1]    (CNT..RCNT zeroed by k_prep block 0)
#define WOFF_BASE  67648      // int[1025] (unused; scan fused into k_scatter)
#define WOFF_CURS  68736      // int[1024] zero-based scatter cursor (zeroed by prep)
#define WOFF_ORDER 69760      // int[65536]
#define WOFF_ET    136320     // float[131072] (K x D), 16B aligned
#define WOFF_PART  267392     // float[131072] (K x D) atomic segment sums
#define WOFF_CSORT 398464     // int[65536] code of each sorted slot
#define WOFF_RLIST 791680     // int[65536]
#define WOFF_EF    857216     // ushort[131072] frag-ordered fp16 of -2E

// ---- output offsets (in floats), reference return order ----
#define OOFF_Q     0          // [16,4096,128]
#define OOFF_DIFF  8388608    // scalar
#define OOFF_CODE  8388609    // [16,4096]
#define OOFF_NEMB  8454145    // [128,1024]
#define OOFF_NCS   8585217    // [1024]
#define OOFF_NMEAN 8586241    // [128,1024]

__device__ __forceinline__ unsigned umin32(unsigned a, unsigned b) { return a < b ? a : b; }
__device__ __forceinline__ unsigned umax32(unsigned a, unsigned b) { return a > b ? a : b; }

// async global->LDS 16B per lane (direct DMA, no VGPR round-trip)
__device__ __forceinline__ void gld16(const unsigned short* g, unsigned short* l) {
    __builtin_amdgcn_global_load_lds(
        (const __attribute__((address_space(1))) unsigned int*)g,
        (__attribute__((address_space(3))) unsigned int*)l, 16, 0, 0);
}

// -------------------------------------------------------------------
// Fused prep: E [D][K] -> Et [K][D], fp16 frag plane Ef of -2E, e2,
// cnt/ssq/rcnt zeroing (block 0), zc zeroing (block 1), part1 zeroing.
__launch_bounds__(256)
__global__ void k_prep(const float* __restrict__ E, float* __restrict__ Et,
                       unsigned short* __restrict__ Ef, float* __restrict__ e2,
                       int* __restrict__ cnt, int* __restrict__ zc,
                       float* __restrict__ part1) {
    __shared__ float tile[128 * 17];   // tile[d][cc], pad 17 vs 16
    __shared__ float e2s[16];
    int tid = threadIdx.x;
    int b = blockIdx.x;                // 0..63
    int c0 = b * 16;
    if (b == 0) {
        for (int i = tid; i < 1026; i += 256) cnt[i] = 0;   // cnt[1024], ssq, rcnt
    }
    if (b == 1) {
        for (int i = tid; i < 1024; i += 256) zc[i] = 0;    // scatter cursor
    }
    // zero part1 (K*D floats, 2048 per block)
    #pragma unroll
    for (int i = 0; i < 8; ++i) part1[b * 2048 + i * 256 + tid] = 0.f;
    if (tid < 16) e2s[tid] = 0.f;
    // ---- load E columns c0..c0+15 (2048 floats) ----
    #pragma unroll
    for (int i = 0; i < 8; ++i) {
        int idx = i * 256 + tid;       // 0..2047
        int d = idx >> 4, cc = idx & 15;
        tile[d * 17 + cc] = E[d * K_ + c0 + cc];
    }
    __syncthreads();
    // ---- write Et rows (coalesced, conflict-free via pad) ----
    #pragma unroll
    for (int i = 0; i < 8; ++i) {
        int idx = i * 256 + tid;
        int cc = idx >> 7, d = idx & 127;
        Et[(size_t)(c0 + cc) * D_ + d] = tile[d * 17 + cc];
    }
    // ---- Ef frags + e2 ----
    int L = tid & 63, s = tid >> 6;
    int cc = L & 15;
    int d0 = s * 32 + ((L >> 4) << 3);
    unsigned short h[8];
    float sq = 0.f;
    #pragma unroll
    for (int j = 0; j < 8; ++j) {
        float e = tile[(d0 + j) * 17 + cc];
        sq = fmaf(e, e, sq);
        h[j] = __half_as_ushort(__float2half(-2.f * e));
    }
    int T = b * 256 + tid;
    #pragma unroll
    for (int j = 0; j < 8; ++j) Ef[T * 8 + j] = h[j];
    atomicAdd(&e2s[cc], sq);
    __syncthreads();
    if (tid < 16) {
        e2[c0 + tid] = e2s[tid];
    }
}

// -------------------------------------------------------------------
// MFMA argmin, PAIR-WISE barriers: 4-buffer LDS ring, one rendezvous
// per 2 chunks (8 barriers vs 16). Order per pair p:
//   vmcnt(0)  -- pair-p loads (the only outstanding vmem) retired
//   s_barrier -- ALL waves' pair-p loads retired AND all waves done
//                reading pair p-1's slots (computed before this barrier)
//   stage pair p+1 into slots {(2p+2)&3,(2p+3)&3}  (== pair p-1's slots,
//                WAR-safe by the barrier argument; disjoint from pair p's
//                compute slots {2p&3,(2p+1)&3})
//   compute chunks 2p, 2p+1
// Prefetch depth = 2 chunks of compute. Bound (512,4) = measured best
// (R4 55.4us; bound-2 R8 57.7; R5/R6 showed bound>=4 on the SMALL kernel
// spills but this 512-thr shape fits in 64 VGPR cleanly).
// Keys: dist' = e2 - 2x.e + 96, clamped to [0.5,508] (binade < 512 ->
// 10-bit trunc ULP <= 0.03125; clamped outliers => d1=d2=d3 => flagged).
// Top-3 certifies: d3-d1 >= M2: argmin in {i1,i2}; d2-d1 < M1 -> exact
// fp32 pair inline. d3-d1 < M2 (rare): full K rescan in k_fix.
__launch_bounds__(512, 4)
__global__ void k_argmin_mfma(const float* __restrict__ x, const unsigned short* __restrict__ Ef,
                              const float* __restrict__ e2,
                              int* __restrict__ code_i, float* __restrict__ code_f,
                              int* __restrict__ cnt, int* __restrict__ rcnt,
                              int* __restrict__ rlist, const float* __restrict__ Et) {
    __shared__ unsigned short Bs[4][8192];   // 4 x 16 KB chunk ring
    __shared__ float e2s[K_];
    int tid = threadIdx.x;
    int w = tid >> 6, L = tid & 63, quad = L >> 4, col = L & 15;
    int mg = w >> 1, ng = w & 1;             // mg 0..3 (32-token groups), ng 0..1 (code half)
    int n0 = blockIdx.x * 128;

    for (int i = tid; i < K_; i += 512) e2s[i] = e2[i];

    // ---- A fragments (32 tokens/wave, fp16) ----
    half8 ah[2][4];
    #pragma unroll
    for (int mt = 0; mt < 2; ++mt) {
        int tok = n0 + (2 * mg + mt) * 16 + col;
        #pragma unroll
        for (int s = 0; s < 4; ++s) {
            const float* p = x + (size_t)tok * D_ + s * 32 + quad * 8;
            float4 u0 = *(const float4*)(p);
            float4 u1 = *(const float4*)(p + 4);
            ah[mt][s][0] = (_Float16)u0.x; ah[mt][s][1] = (_Float16)u0.y;
            ah[mt][s][2] = (_Float16)u0.z; ah[mt][s][3] = (_Float16)u0.w;
            ah[mt][s][4] = (_Float16)u1.x; ah[mt][s][5] = (_Float16)u1.y;
            ah[mt][s][6] = (_Float16)u1.z; ah[mt][s][7] = (_Float16)u1.w;
        }
    }

    unsigned k1[2][4], k2[2][4], k3[2][4];
    #pragma unroll
    for (int mt = 0; mt < 2; ++mt)
        #pragma unroll
        for (int r = 0; r < 4; ++r) {
            k1[mt][r] = 0xFFFFFFFFu; k2[mt][r] = 0xFFFFFFFFu; k3[mt][r] = 0xFFFFFFFFu;
        }

    __syncthreads();                          // e2s visible; x loads drained

    // ---- prologue: stage pair 0 (chunks 0,1 -> slots 0,1) ----
    #pragma unroll
    for (int c = 0; c < 2; ++c)
        #pragma unroll
        for (int i = 0; i < 2; ++i) {
            int o = (w * 2 + i) * 512;
            gld16(Ef + c * 8192 + o + L * 8, &Bs[c][o]);
        }

    #pragma unroll
    for (int p = 0; p < 8; ++p) {
        // pair-p loads are the only outstanding vmem; they were issued
        // one full pair-compute earlier.
        asm volatile("s_waitcnt vmcnt(0)" ::: "memory");
        __builtin_amdgcn_s_barrier();
        asm volatile("" ::: "memory");

        // ---- stage pair p+1 (overlaps compute of pair p) ----
        if (p < 7) {
            #pragma unroll
            for (int c = 0; c < 2; ++c) {
                int ch = 2 * p + 2 + c;
                const unsigned short* src = Ef + ch * 8192;
                int sl = ch & 3;
                #pragma unroll
                for (int i = 0; i < 2; ++i) {
                    int o = (w * 2 + i) * 512;
                    gld16(src + o + L * 8, &Bs[sl][o]);
                }
            }
        }

        // ---- compute chunks 2p, 2p+1 ----
        #pragma unroll
        for (int hh = 0; hh < 2; ++hh) {
            int q = 2 * p + hh;
            const unsigned short* Bp = &Bs[q & 3][0];

            // acc init = e2[code] + BIAS
            float evb[2];
            #pragma unroll
            for (int nn = 0; nn < 2; ++nn)
                evb[nn] = e2s[q * 64 + (2 * ng + nn) * 16 + col] + BIAS_;
            f32x4 acc[2][2];
            #pragma unroll
            for (int mt = 0; mt < 2; ++mt)
                #pragma unroll
                for (int nn = 0; nn < 2; ++nn)
                    #pragma unroll
                    for (int r = 0; r < 4; ++r)
                        acc[mt][nn][r] = evb[nn];

            // 16 MFMA: 4 k-steps x 2 n-subs x 2 m-tiles
            #pragma unroll
            for (int s = 0; s < 4; ++s) {
                half8 bh[2];
                #pragma unroll
                for (int nn = 0; nn < 2; ++nn) {
                    int off = (((2 * ng + nn) * 4 + s) * 64 + L) * 8;
                    bh[nn] = *(const half8*)(Bp + off);
                }
                #pragma unroll
                for (int nn = 0; nn < 2; ++nn)
                    #pragma unroll
                    for (int mt = 0; mt < 2; ++mt)
                        acc[mt][nn] = __builtin_amdgcn_mfma_f32_16x16x32_f16(ah[mt][s], bh[nn], acc[mt][nn], 0, 0, 0);
            }

            // clamp to [0.5,508] + packed-key top-3 insert
            #pragma unroll
            for (int nn = 0; nn < 2; ++nn) {
                unsigned cb = (unsigned)(q * 64 + (2 * ng + nn) * 16 + col);
                #pragma unroll
                for (int mt = 0; mt < 2; ++mt)
                    #pragma unroll
                    for (int r = 0; r < 4; ++r) {
                        float dc = fminf(fmaxf(acc[mt][nn][r], CLMIN_), CLMAX_);
                        unsigned key = (__float_as_uint(dc) & 0xFFFFFC00u) | cb;
                        unsigned m1 = umax32(k1[mt][r], key);
                        k1[mt][r]   = umin32(k1[mt][r], key);
                        unsigned m2 = umax32(k2[mt][r], m1);
                        k2[mt][r]   = umin32(k2[mt][r], m1);
                        k3[mt][r]   = umin32(k3[mt][r], m2);
                    }
            }
        }
    }

    // ---- cross-lane merge of sorted triples over 16 cols ----
    __syncthreads();
    unsigned* mk1 = (unsigned*)&Bs[0][0];     // [128 tokens][2 halves] x 3
    unsigned* mk2 = mk1 + 256;
    unsigned* mk3 = mk2 + 256;

    #pragma unroll
    for (int mt = 0; mt < 2; ++mt) {
        #pragma unroll
        for (int r = 0; r < 4; ++r) {
            unsigned a = k1[mt][r], b = k2[mt][r], c = k3[mt][r];
            #pragma unroll
            for (int m = 1; m < 16; m <<= 1) {
                unsigned ao = (unsigned)__shfl_xor((int)a, m);
                unsigned bo = (unsigned)__shfl_xor((int)b, m);
                unsigned co = (unsigned)__shfl_xor((int)c, m);
                unsigned t1 = umax32(a, ao);
                a           = umin32(a, ao);
                unsigned s2 = umin32(b, bo);
                unsigned u  = umax32(t1, s2);
                b           = umin32(t1, s2);
                c           = umin32(u, umin32(c, co));
            }
            if (col == 0) {
                int tl = (2 * mg + mt) * 16 + quad * 4 + r;
                mk1[tl * 2 + ng] = a;
                mk2[tl * 2 + ng] = b;
                mk3[tl * 2 + ng] = c;
            }
        }
    }
    __syncthreads();
    if (tid < 128) {
        unsigned a1 = mk1[tid * 2], b1 = mk1[tid * 2 + 1];
        unsigned a2 = mk2[tid * 2], b2 = mk2[tid * 2 + 1];
        unsigned a3 = mk3[tid * 2], b3 = mk3[tid * 2 + 1];
        unsigned t1 = umax32(a1, b1);
        unsigned kk1 = umin32(a1, b1);
        unsigned s2 = umin32(a2, b2);
        unsigned kk2 = umin32(t1, s2);
        unsigned u  = umax32(t1, s2);
        unsigned kk3 = umin32(u, umin32(a3, b3));

        int i1 = (int)(kk1 & 1023u), i2 = (int)(kk2 & 1023u);
        float d1 = __uint_as_float(kk1 & 0xFFFFFC00u);
        float d2 = __uint_as_float(kk2 & 0xFFFFFC00u);
        float d3 = __uint_as_float(kk3 & 0xFFFFFC00u);
        int tok = n0 + tid;

        if (d3 - d1 < M2_) {
            // 3+ codes inside the uncertainty band: full exact rescan later
            code_i[tok] = i1;
            code_f[tok] = (float)i1;
            atomicAdd(cnt + i1, 1);
            int p = atomicAdd(rcnt, 1);
            rlist[p] = tok;
        } else {
            int win = i1;
            if (d2 - d1 < M1_) {
                // exact fp32 pair decision, inline (true argmin is i1 or i2)
                const float* xr = x  + (size_t)tok * D_;
                const float* ea = Et + (size_t)i1 * D_;
                const float* eb = Et + (size_t)i2 * D_;
                float s1 = 0.f, sB = 0.f;
                #pragma unroll 4
                for (int dd = 0; dd < D_; dd += 4) {
                    float4 xv = *(const float4*)(xr + dd);
                    float4 av = *(const float4*)(ea + dd);
                    float4 bv = *(const float4*)(eb + dd);
                    s1 = fmaf(xv.x, av.x, s1); s1 = fmaf(xv.y, av.y, s1);
                    s1 = fmaf(xv.z, av.z, s1); s1 = fmaf(xv.w, av.w, s1);
                    sB = fmaf(xv.x, bv.x, sB); sB = fmaf(xv.y, bv.y, sB);
                    sB = fmaf(xv.z, bv.z, sB); sB = fmaf(xv.w, bv.w, sB);
                }
                float ex1 = e2s[i1] - 2.f * s1;
                float ex2 = e2s[i2] - 2.f * sB;
                if (ex2 < ex1 || (ex2 == ex1 && i2 < i1)) win = i2;
            }
            code_i[tok] = win;
            code_f[tok] = (float)win;
            atomicAdd(cnt + win, 1);
        }
    }
}

// -------------------------------------------------------------------
// exact fp32 re-argmin for triple-ambiguous tokens (rare)
__launch_bounds__(256)
__global__ void k_fix(const float* __restrict__ x, const float* __restrict__ Et,
                      const float* __restrict__ e2, const int* __restrict__ rcnt,
                      const int* __restrict__ rlist, int* __restrict__ code_i,
                      float* __restrict__ code_f, int* __restrict__ cnt) {
    __shared__ float4 xs[32];
    __shared__ float sd[8];
    __shared__ int   si[8];
    int tid = threadIdx.x;
    int lane = tid & 63, w = tid >> 6;
    int half = lane >> 5;
    int q32  = lane & 31;
    int slot = w * 2 + half;     // 0..7: codes c ≡ slot (mod 8)
    int nr = *rcnt;
    for (int it = blockIdx.x; it < nr; it += gridDim.x) {
        __syncthreads();
        int tok = rlist[it];
        if (tid < 32) xs[tid] = ((const float4*)(x + (size_t)tok * D_))[tid];
        __syncthreads();
        float4 xv = xs[q32];
        float bd = INFINITY; int bb = 0;
        for (int c0 = 0; c0 < K_; c0 += 8) {
            int c = c0 + slot;
            float4 e = ((const float4*)(Et + (size_t)c * D_))[q32];
            float dot = xv.x * e.x + xv.y * e.y + xv.z * e.z + xv.w * e.w;
            dot += __shfl_xor(dot, 1);
            dot += __shfl_xor(dot, 2);
            dot += __shfl_xor(dot, 4);
            dot += __shfl_xor(dot, 8);
            dot += __shfl_xor(dot, 16);
            float dist = e2[c] - 2.f * dot;
            if (dist < bd) { bd = dist; bb = c; }   // c ascending => first-min
        }
        if (q32 == 0) { sd[slot] = bd; si[slot] = bb; }
        __syncthreads();
        if (tid == 0) {
            float fb = sd[0]; int fi = si[0];
            #pragma unroll
            for (int s = 1; s < 8; ++s) {
                if (sd[s] < fb || (sd[s] == fb && si[s] < fi)) { fb = sd[s]; fi = si[s]; }
            }
            int ob = code_i[tok];
            if (fi != ob) {
                code_i[tok] = fi;
                code_f[tok] = (float)fi;
                atomicAdd(cnt + ob, -1);
                atomicAdd(cnt + fi, 1);
            }
        }
    }
}

// -------------------------------------------------------------------
// Fused scan+scatter: each block redundantly computes the exclusive
// scan of cnt[1024] in LDS (few us of redundant work, kills the serial
// 1-block k_scan launch), then scatters its 256 tokens via
// base[c] + atomicAdd(zc+c,1). Scan logic exercised in R9's k_coop.
__launch_bounds__(256)
__global__ void k_scatter(const int* __restrict__ cnt, const int* __restrict__ code_i,
                          int* __restrict__ zc, int* __restrict__ order,
                          int* __restrict__ csort) {
    __shared__ int sbase[1024];
    __shared__ int wtot[4];
    int t = threadIdx.x;
    int lane = t & 63, wv = t >> 6;
    int c4[4];
    #pragma unroll
    for (int j = 0; j < 4; ++j) c4[j] = cnt[4 * t + j];
    int s = c4[0] + c4[1] + c4[2] + c4[3];
    int ps = s;
    #pragma unroll
    for (int m = 1; m < 64; m <<= 1) {
        int o = __shfl_up(ps, m);
        if (lane >= m) ps += o;
    }
    if (lane == 63) wtot[wv] = ps;
    __syncthreads();
    int woff = 0;
    for (int i = 0; i < 4; ++i) if (i < wv) woff += wtot[i];
    int run = woff + ps - s;
    #pragma unroll
    for (int j = 0; j < 4; ++j) {
        sbase[4 * t + j] = run;    // exclusive base of code 4t+j
        run += c4[j];
    }
    __syncthreads();

    int n = blockIdx.x * 256 + t;
    int c = code_i[n];
    int pos = sbase[c] + atomicAdd(zc + c, 1);
    order[pos] = n;
    csort[pos] = c;
}

// -------------------------------------------------------------------
// UNIFORM-WORK fused segment-sum + dequant/ST/ssq, 256 threads:
// block i owns sorted slots [32i,32i+32) as TWO independent 16-slot
// halves (tid>>7), each with its own running-sum flush chain (flushes
// are atomic -> correct regardless of which half flushes). Halves the
// serial gather chain of the 128-thr version and doubles waves/CU.
__launch_bounds__(256)
__global__ void k_segdeq(const float* __restrict__ x, const float* __restrict__ Et,
                         const int* __restrict__ order, const int* __restrict__ csort,
                         float* __restrict__ part1, float* __restrict__ outq,
                         float* __restrict__ ssqp) {
    __shared__ int sn[WSEG], sc[WSEG];
    __shared__ float wsum[4];
    int tid = threadIdx.x;
    int d = tid & 127;
    int h = tid >> 7;                       // half 0/1
    int i0 = blockIdx.x * WSEG;
    if (tid < WSEG) { sn[tid] = order[i0 + tid]; sc[tid] = csort[i0 + tid]; }
    __syncthreads();
    int s0 = h * 16;
    int cprev = sc[s0];
    float eq = Et[(size_t)cprev * D_ + d];
    float acc = 0.f, ssql = 0.f;
    float xv = x[(size_t)sn[s0] * D_ + d];
    #pragma unroll 4
    for (int j = 0; j < 16; ++j) {
        int sj = s0 + j;
        float xn = (j < 15) ? x[(size_t)sn[sj + 1] * D_ + d] : 0.f;  // prefetch
        int c = sc[sj];
        if (c != cprev) {                      // wave-uniform branch
            atomicAdd(&part1[(size_t)cprev * D_ + d], acc);
            acc = 0.f;
            eq = Et[(size_t)c * D_ + d];
            cprev = c;
        }
        float qv = xv + (eq - xv);             // reference fp32 rounding
        outq[(size_t)sn[sj] * D_ + d] = qv;
        float t = qv - xv;
        ssql = fmaf(t, t, ssql);
        acc += xv;
        xv = xn;
    }
    atomicAdd(&part1[(size_t)cprev * D_ + d], acc);

    // block-reduce ssql (4 waves of 64) -> one global atomic
    #pragma unroll
    for (int off = 32; off > 0; off >>= 1) ssql += __shfl_down(ssql, off);
    if ((tid & 63) == 0) wsum[tid >> 6] = ssql;
    __syncthreads();
    if (tid == 0) atomicAdd(ssqp, (wsum[0] + wsum[1]) + (wsum[2] + wsum[3]));
}

// -------------------------------------------------------------------
// fused stats + embed: each block redundantly reduces n; block 0 also
// writes out_ncs + out_diff. Then EMA mean + divide for its 256 elems.
__launch_bounds__(256)
__global__ void k_embed(const float* __restrict__ em, const float* __restrict__ part1,
                        const int* __restrict__ cnt, const float* __restrict__ csz,
                        const float* __restrict__ ssqp, float* __restrict__ out_nmean,
                        float* __restrict__ out_nemb, float* __restrict__ out_ncs,
                        float* __restrict__ out_diff) {
    int tid = threadIdx.x;
    __shared__ float red[256];

    // ---- n = sum_k ncs_k (redundant per block) ----
    float ls = 0.f;
    for (int j = tid; j < K_; j += 256) ls += csz[j] * DECAY_ + OMD_ * (float)cnt[j];
    red[tid] = ls;
    __syncthreads();
    for (int off = 128; off > 0; off >>= 1) {
        if (tid < off) red[tid] += red[tid + off];
        __syncthreads();
    }
    float n = red[0];
    __syncthreads();

    if (blockIdx.x == 0) {
        for (int j = tid; j < K_; j += 256)
            out_ncs[j] = csz[j] * DECAY_ + OMD_ * (float)cnt[j];
        if (tid == 0) *out_diff = VQC_ * ssqp[0] / (float)(N_ * D_);
    }

    int i = blockIdx.x * 256 + tid;           // over D*K, layout [D][K]
    int k = i & (K_ - 1);
    int d = i >> 10;
    float ncs_k = csz[k] * DECAY_ + OMD_ * (float)cnt[k];
    float csk = (ncs_k + EPS_) / (n + (float)K_ * EPS_) * n;
    float es = part1[(size_t)k * D_ + d];
    float nm = em[i] * DECAY_ + OMD_ * es;
    out_nmean[i] = nm;
    out_nemb[i]  = nm / csk;
}

// -------------------------------------------------------------------
extern "C" void kernel_launch(void* const* d_in, const int* in_sizes, int n_in,
                              void* d_out, int out_size, void* d_ws, size_t ws_size,
                              hipStream_t stream) {
    const float* x   = (const float*)d_in[0];   // [16,4096,128]
    const float* E   = (const float*)d_in[1];   // [128,1024]
    const float* csz = (const float*)d_in[2];   // [1024]
    const float* em  = (const float*)d_in[3];   // [128,1024]
    float* out = (float*)d_out;
    float* W   = (float*)d_ws;

    int*   code_i = (int*)(W + WOFF_CODE);
    float* e2     = W + WOFF_E2;
    int*   cnt    = (int*)(W + WOFF_CNT);
    float* ssqp   = W + WOFF_SSQ;
    int*   rcnt   = (int*)(W + WOFF_RCNT);
    int*   zc     = (int*)(W + WOFF_CURS);
    int*   order  = (int*)(W + WOFF_ORDER);
    float* Et     = W + WOFF_ET;
    float* part1  = W + WOFF_PART;
    int*   csort  = (int*)(W + WOFF_CSORT);
    int*   rlist  = (int*)(W + WOFF_RLIST);
    unsigned short* Ef = (unsigned short*)(W + WOFF_EF);

    k_prep<<<64, 256, 0, stream>>>(E, Et, Ef, e2, cnt, zc, part1);
    k_argmin_mfma<<<N_ / 128, 512, 0, stream>>>(x, Ef, e2, code_i,
                                                out + OOFF_CODE, cnt, rcnt, rlist, Et);
    k_fix<<<1024, 256, 0, stream>>>(x, Et, e2, rcnt, rlist, code_i, out + OOFF_CODE, cnt);
    k_scatter<<<N_ / 256, 256, 0, stream>>>(cnt, code_i, zc, order, csort);
    k_segdeq<<<N_ / WSEG, 256, 0, stream>>>(x, Et, order, csort, part1,
                                            out + OOFF_Q, ssqp);
    k_embed<<<(D_ * K_) / 256, 256, 0, stream>>>(em, part1, cnt, csz, ssqp,
                                                 out + OOFF_NMEAN, out + OOFF_NEMB,
                                                 out + OOFF_NCS, out + OOFF_DIFF);
}

// Round 12
// 233.456 us; speedup vs baseline: 2.3840x; 1.0019x over previous
//
#include <hip/hip_runtime.h>
#include <hip/hip_fp16.h>
#include <math.h>

#define D_ 128
#define K_ 1024
#define N_ 65536
#define DECAY_ 0.99f
#define OMD_ 0.01f
#define EPS_ 1e-5f
#define VQC_ 0.25f
#define M1_ 0.14f     // pair band: 2*eps(fp16 dot) + 2*keytrunc
#define M2_ 0.14f     // triple band -> full K rescan
#define BIAS_ 96.0f   // positivity shift for e2-2xe (argmin-invariant per token)
#define CLMIN_ 0.5f
#define CLMAX_ 508.0f // keys < 512 => trunc ULP 2^-5; clamped => triple-flagged
#define WSEG 32       // tokens per k_segdeq block (2 x 16-slot halves)

typedef __attribute__((ext_vector_type(8))) _Float16 half8;
typedef __attribute__((ext_vector_type(4))) float f32x4;

// ---- workspace offsets (in 4-byte elements) ----
#define WOFF_CODE  0          // int[65536]
#define WOFF_E2    65536      // float[1024]
#define WOFF_CNT   66560      // int[1024]
#define WOFF_SSQ   67584      // float[1]  (zeroed by k_prep block 0)
#define WOFF_RCNT  67585      // int[1]    (CNT..RCNT zeroed by k_prep block 0)
#define WOFF_BASE  67648      // int[1025] (unused; scan fused into k_scatter)
#define WOFF_CURS  68736      // int[1024] zero-based scatter cursor (zeroed by prep)
#define WOFF_ORDER 69760      // int[65536]
#define WOFF_ET    136320     // float[131072] (K x D), 16B aligned
#define WOFF_PART  267392     // float[131072] (K x D) atomic segment sums
#define WOFF_CSORT 398464     // int[65536] code of each sorted slot
#define WOFF_RLIST 791680     // int[65536]
#define WOFF_EF    857216     // ushort[131072] frag-ordered fp16 of -2E

// ---- output offsets (in floats), reference return order ----
#define OOFF_Q     0          // [16,4096,128]
#define OOFF_DIFF  8388608    // scalar
#define OOFF_CODE  8388609    // [16,4096]
#define OOFF_NEMB  8454145    // [128,1024]
#define OOFF_NCS   8585217    // [1024]
#define OOFF_NMEAN 8586241    // [128,1024]

__device__ __forceinline__ unsigned umin32(unsigned a, unsigned b) { return a < b ? a : b; }
__device__ __forceinline__ unsigned umax32(unsigned a, unsigned b) { return a > b ? a : b; }

// async global->LDS 16B per lane (direct DMA, no VGPR round-trip)
__device__ __forceinline__ void gld16(const unsigned short* g, unsigned short* l) {
    __builtin_amdgcn_global_load_lds(
        (const __attribute__((address_space(1))) unsigned int*)g,
        (__attribute__((address_space(3))) unsigned int*)l, 16, 0, 0);
}

// -------------------------------------------------------------------
// Fused prep: E [D][K] -> Et [K][D], fp16 frag plane Ef of -2E, e2,
// cnt/ssq/rcnt zeroing (block 0), zc zeroing (block 1), part1 zeroing.
__launch_bounds__(256)
__global__ void k_prep(const float* __restrict__ E, float* __restrict__ Et,
                       unsigned short* __restrict__ Ef, float* __restrict__ e2,
                       int* __restrict__ cnt, int* __restrict__ zc,
                       float* __restrict__ part1) {
    __shared__ float tile[128 * 17];   // tile[d][cc], pad 17 vs 16
    __shared__ float e2s[16];
    int tid = threadIdx.x;
    int b = blockIdx.x;                // 0..63
    int c0 = b * 16;
    if (b == 0) {
        for (int i = tid; i < 1026; i += 256) cnt[i] = 0;   // cnt[1024], ssq, rcnt
    }
    if (b == 1) {
        for (int i = tid; i < 1024; i += 256) zc[i] = 0;    // scatter cursor
    }
    // zero part1 (K*D floats, 2048 per block)
    #pragma unroll
    for (int i = 0; i < 8; ++i) part1[b * 2048 + i * 256 + tid] = 0.f;
    if (tid < 16) e2s[tid] = 0.f;
    // ---- load E columns c0..c0+15 (2048 floats) ----
    #pragma unroll
    for (int i = 0; i < 8; ++i) {
        int idx = i * 256 + tid;       // 0..2047
        int d = idx >> 4, cc = idx & 15;
        tile[d * 17 + cc] = E[d * K_ + c0 + cc];
    }
    __syncthreads();
    // ---- write Et rows (coalesced, conflict-free via pad) ----
    #pragma unroll
    for (int i = 0; i < 8; ++i) {
        int idx = i * 256 + tid;
        int cc = idx >> 7, d = idx & 127;
        Et[(size_t)(c0 + cc) * D_ + d] = tile[d * 17 + cc];
    }
    // ---- Ef frags + e2 ----
    int L = tid & 63, s = tid >> 6;
    int cc = L & 15;
    int d0 = s * 32 + ((L >> 4) << 3);
    unsigned short h[8];
    float sq = 0.f;
    #pragma unroll
    for (int j = 0; j < 8; ++j) {
        float e = tile[(d0 + j) * 17 + cc];
        sq = fmaf(e, e, sq);
        h[j] = __half_as_ushort(__float2half(-2.f * e));
    }
    int T = b * 256 + tid;
    #pragma unroll
    for (int j = 0; j < 8; ++j) Ef[T * 8 + j] = h[j];
    atomicAdd(&e2s[cc], sq);
    __syncthreads();
    if (tid < 16) {
        e2[c0 + tid] = e2s[tid];
    }
}

// -------------------------------------------------------------------
// MFMA argmin — REVERTED to the measured-best R4 configuration
// (55.3-55.9us across two independent benches): 3-buffer LDS ring
// (52 KB), stage-AFTER-compute into slot (q+2)%3 (WAR-safe: stage(q+2)
// issues after barrier(q), which all waves cross only after
// compute(q-1), the last reader of that slot), counted vmcnt(2) keeps
// the NEXT chunk's DMA in flight across every barrier (R11's pair-wise
// vmcnt(0) scheme drained the queue at each rendezvous: 80.6us, +45%).
// Bound (512,4): VGPR 64, no spill (bound-2 chose 72 and was slower).
// Keys: dist' = e2 - 2x.e + 96, clamped to [0.5,508] (binade < 512 ->
// 10-bit trunc ULP <= 0.03125; clamped outliers => d1=d2=d3 => flagged).
// Top-3 certifies: d3-d1 >= M2: argmin in {i1,i2}; d2-d1 < M1 -> exact
// fp32 pair inline. d3-d1 < M2 (rare): full K rescan in k_fix.
__launch_bounds__(512, 4)
__global__ void k_argmin_mfma(const float* __restrict__ x, const unsigned short* __restrict__ Ef,
                              const float* __restrict__ e2,
                              int* __restrict__ code_i, float* __restrict__ code_f,
                              int* __restrict__ cnt, int* __restrict__ rcnt,
                              int* __restrict__ rlist, const float* __restrict__ Et) {
    __shared__ unsigned short Bs[3][8192];   // 3 x 16 KB chunk ring
    __shared__ float e2s[K_];
    int tid = threadIdx.x;
    int w = tid >> 6, L = tid & 63, quad = L >> 4, col = L & 15;
    int mg = w >> 1, ng = w & 1;             // mg 0..3 (32-token groups), ng 0..1 (code half)
    int n0 = blockIdx.x * 128;

    for (int i = tid; i < K_; i += 512) e2s[i] = e2[i];

    // ---- A fragments (32 tokens/wave, fp16) ----
    half8 ah[2][4];
    #pragma unroll
    for (int mt = 0; mt < 2; ++mt) {
        int tok = n0 + (2 * mg + mt) * 16 + col;
        #pragma unroll
        for (int s = 0; s < 4; ++s) {
            const float* p = x + (size_t)tok * D_ + s * 32 + quad * 8;
            float4 u0 = *(const float4*)(p);
            float4 u1 = *(const float4*)(p + 4);
            ah[mt][s][0] = (_Float16)u0.x; ah[mt][s][1] = (_Float16)u0.y;
            ah[mt][s][2] = (_Float16)u0.z; ah[mt][s][3] = (_Float16)u0.w;
            ah[mt][s][4] = (_Float16)u1.x; ah[mt][s][5] = (_Float16)u1.y;
            ah[mt][s][6] = (_Float16)u1.z; ah[mt][s][7] = (_Float16)u1.w;
        }
    }

    unsigned k1[2][4], k2[2][4], k3[2][4];
    #pragma unroll
    for (int mt = 0; mt < 2; ++mt)
        #pragma unroll
        for (int r = 0; r < 4; ++r) {
            k1[mt][r] = 0xFFFFFFFFu; k2[mt][r] = 0xFFFFFFFFu; k3[mt][r] = 0xFFFFFFFFu;
        }

    __syncthreads();                          // e2s visible; nothing else in flight

    // ---- prologue: stage chunks 0,1 into slots 0,1 (2 ops each/wave) ----
    #pragma unroll
    for (int i = 0; i < 2; ++i) {
        int o = (w * 2 + i) * 512;
        gld16(Ef + o + L * 8, &Bs[0][o]);
    }
    #pragma unroll
    for (int i = 0; i < 2; ++i) {
        int o = (w * 2 + i) * 512;
        gld16(Ef + 8192 + o + L * 8, &Bs[1][o]);
    }

    #pragma unroll
    for (int q = 0; q < 16; ++q) {
        // outstanding here: chunk q (2 ops) + chunk q+1 (2 ops).
        // vmcnt(2) retires MY chunk-q loads; barrier => ALL waves' retired.
        if (q < 15) asm volatile("s_waitcnt vmcnt(2)" ::: "memory");
        else        asm volatile("s_waitcnt vmcnt(0)" ::: "memory");
        __builtin_amdgcn_s_barrier();
        asm volatile("" ::: "memory");

        const unsigned short* Bp = &Bs[q % 3][0];

        // ---- acc init = e2[code] + BIAS ----
        float evb[2];
        #pragma unroll
        for (int nn = 0; nn < 2; ++nn)
            evb[nn] = e2s[q * 64 + (2 * ng + nn) * 16 + col] + BIAS_;
        f32x4 acc[2][2];
        #pragma unroll
        for (int mt = 0; mt < 2; ++mt)
            #pragma unroll
            for (int nn = 0; nn < 2; ++nn)
                #pragma unroll
                for (int r = 0; r < 4; ++r)
                    acc[mt][nn][r] = evb[nn];

        // ---- 16 MFMA: 4 k-steps x 2 n-subs x 2 m-tiles ----
        #pragma unroll
        for (int s = 0; s < 4; ++s) {
            half8 bh[2];
            #pragma unroll
            for (int nn = 0; nn < 2; ++nn) {
                int off = (((2 * ng + nn) * 4 + s) * 64 + L) * 8;
                bh[nn] = *(const half8*)(Bp + off);
            }
            #pragma unroll
            for (int nn = 0; nn < 2; ++nn)
                #pragma unroll
                for (int mt = 0; mt < 2; ++mt)
                    acc[mt][nn] = __builtin_amdgcn_mfma_f32_16x16x32_f16(ah[mt][s], bh[nn], acc[mt][nn], 0, 0, 0);
        }

        // ---- clamp to [0.5,508] + packed-key top-3 insert ----
        #pragma unroll
        for (int nn = 0; nn < 2; ++nn) {
            unsigned cb = (unsigned)(q * 64 + (2 * ng + nn) * 16 + col);
            #pragma unroll
            for (int mt = 0; mt < 2; ++mt)
                #pragma unroll
                for (int r = 0; r < 4; ++r) {
                    float dc = fminf(fmaxf(acc[mt][nn][r], CLMIN_), CLMAX_);
                    unsigned key = (__float_as_uint(dc) & 0xFFFFFC00u) | cb;
                    unsigned m1 = umax32(k1[mt][r], key);
                    k1[mt][r]   = umin32(k1[mt][r], key);
                    unsigned m2 = umax32(k2[mt][r], m1);
                    k2[mt][r]   = umin32(k2[mt][r], m1);
                    k3[mt][r]   = umin32(k3[mt][r], m2);
                }
        }

        // ---- stage chunk q+2 into slot (q+2)%3 (WAR-safe) ----
        if (q < 14) {
            const unsigned short* src = Ef + (q + 2) * 8192;
            int sl = (q + 2) % 3;
            #pragma unroll
            for (int i = 0; i < 2; ++i) {
                int o = (w * 2 + i) * 512;
                gld16(src + o + L * 8, &Bs[sl][o]);
            }
        }
    }

    // ---- cross-lane merge of sorted triples over 16 cols ----
    __syncthreads();
    unsigned* mk1 = (unsigned*)&Bs[0][0];     // [128 tokens][2 halves] x 3
    unsigned* mk2 = mk1 + 256;
    unsigned* mk3 = mk2 + 256;

    #pragma unroll
    for (int mt = 0; mt < 2; ++mt) {
        #pragma unroll
        for (int r = 0; r < 4; ++r) {
            unsigned a = k1[mt][r], b = k2[mt][r], c = k3[mt][r];
            #pragma unroll
            for (int m = 1; m < 16; m <<= 1) {
                unsigned ao = (unsigned)__shfl_xor((int)a, m);
                unsigned bo = (unsigned)__shfl_xor((int)b, m);
                unsigned co = (unsigned)__shfl_xor((int)c, m);
                unsigned t1 = umax32(a, ao);
                a           = umin32(a, ao);
                unsigned s2 = umin32(b, bo);
                unsigned u  = umax32(t1, s2);
                b           = umin32(t1, s2);
                c           = umin32(u, umin32(c, co));
            }
            if (col == 0) {
                int tl = (2 * mg + mt) * 16 + quad * 4 + r;
                mk1[tl * 2 + ng] = a;
                mk2[tl * 2 + ng] = b;
                mk3[tl * 2 + ng] = c;
            }
        }
    }
    __syncthreads();
    if (tid < 128) {
        unsigned a1 = mk1[tid * 2], b1 = mk1[tid * 2 + 1];
        unsigned a2 = mk2[tid * 2], b2 = mk2[tid * 2 + 1];
        unsigned a3 = mk3[tid * 2], b3 = mk3[tid * 2 + 1];
        unsigned t1 = umax32(a1, b1);
        unsigned kk1 = umin32(a1, b1);
        unsigned s2 = umin32(a2, b2);
        unsigned kk2 = umin32(t1, s2);
        unsigned u  = umax32(t1, s2);
        unsigned kk3 = umin32(u, umin32(a3, b3));

        int i1 = (int)(kk1 & 1023u), i2 = (int)(kk2 & 1023u);
        float d1 = __uint_as_float(kk1 & 0xFFFFFC00u);
        float d2 = __uint_as_float(kk2 & 0xFFFFFC00u);
        float d3 = __uint_as_float(kk3 & 0xFFFFFC00u);
        int tok = n0 + tid;

        if (d3 - d1 < M2_) {
            // 3+ codes inside the uncertainty band: full exact rescan later
            code_i[tok] = i1;
            code_f[tok] = (float)i1;
            atomicAdd(cnt + i1, 1);
            int p = atomicAdd(rcnt, 1);
            rlist[p] = tok;
        } else {
            int win = i1;
            if (d2 - d1 < M1_) {
                // exact fp32 pair decision, inline (true argmin is i1 or i2)
                const float* xr = x  + (size_t)tok * D_;
                const float* ea = Et + (size_t)i1 * D_;
                const float* eb = Et + (size_t)i2 * D_;
                float s1 = 0.f, sB = 0.f;
                #pragma unroll 4
                for (int dd = 0; dd < D_; dd += 4) {
                    float4 xv = *(const float4*)(xr + dd);
                    float4 av = *(const float4*)(ea + dd);
                    float4 bv = *(const float4*)(eb + dd);
                    s1 = fmaf(xv.x, av.x, s1); s1 = fmaf(xv.y, av.y, s1);
                    s1 = fmaf(xv.z, av.z, s1); s1 = fmaf(xv.w, av.w, s1);
                    sB = fmaf(xv.x, bv.x, sB); sB = fmaf(xv.y, bv.y, sB);
                    sB = fmaf(xv.z, bv.z, sB); sB = fmaf(xv.w, bv.w, sB);
                }
                float ex1 = e2s[i1] - 2.f * s1;
                float ex2 = e2s[i2] - 2.f * sB;
                if (ex2 < ex1 || (ex2 == ex1 && i2 < i1)) win = i2;
            }
            code_i[tok] = win;
            code_f[tok] = (float)win;
            atomicAdd(cnt + win, 1);
        }
    }
}

// -------------------------------------------------------------------
// exact fp32 re-argmin for triple-ambiguous tokens (rare)
__launch_bounds__(256)
__global__ void k_fix(const float* __restrict__ x, const float* __restrict__ Et,
                      const float* __restrict__ e2, const int* __restrict__ rcnt,
                      const int* __restrict__ rlist, int* __restrict__ code_i,
                      float* __restrict__ code_f, int* __restrict__ cnt) {
    __shared__ float4 xs[32];
    __shared__ float sd[8];
    __shared__ int   si[8];
    int tid = threadIdx.x;
    int lane = tid & 63, w = tid >> 6;
    int half = lane >> 5;
    int q32  = lane & 31;
    int slot = w * 2 + half;     // 0..7: codes c ≡ slot (mod 8)
    int nr = *rcnt;
    for (int it = blockIdx.x; it < nr; it += gridDim.x) {
        __syncthreads();
        int tok = rlist[it];
        if (tid < 32) xs[tid] = ((const float4*)(x + (size_t)tok * D_))[tid];
        __syncthreads();
        float4 xv = xs[q32];
        float bd = INFINITY; int bb = 0;
        for (int c0 = 0; c0 < K_; c0 += 8) {
            int c = c0 + slot;
            float4 e = ((const float4*)(Et + (size_t)c * D_))[q32];
            float dot = xv.x * e.x + xv.y * e.y + xv.z * e.z + xv.w * e.w;
            dot += __shfl_xor(dot, 1);
            dot += __shfl_xor(dot, 2);
            dot += __shfl_xor(dot, 4);
            dot += __shfl_xor(dot, 8);
            dot += __shfl_xor(dot, 16);
            float dist = e2[c] - 2.f * dot;
            if (dist < bd) { bd = dist; bb = c; }   // c ascending => first-min
        }
        if (q32 == 0) { sd[slot] = bd; si[slot] = bb; }
        __syncthreads();
        if (tid == 0) {
            float fb = sd[0]; int fi = si[0];
            #pragma unroll
            for (int s = 1; s < 8; ++s) {
                if (sd[s] < fb || (sd[s] == fb && si[s] < fi)) { fb = sd[s]; fi = si[s]; }
            }
            int ob = code_i[tok];
            if (fi != ob) {
                code_i[tok] = fi;
                code_f[tok] = (float)fi;
                atomicAdd(cnt + ob, -1);
                atomicAdd(cnt + fi, 1);
            }
        }
    }
}

// -------------------------------------------------------------------
// Fused scan+scatter: each block redundantly computes the exclusive
// scan of cnt[1024] in LDS (kills the serial 1-block k_scan launch),
// then scatters its 256 tokens via base[c] + atomicAdd(zc+c,1).
__launch_bounds__(256)
__global__ void k_scatter(const int* __restrict__ cnt, const int* __restrict__ code_i,
                          int* __restrict__ zc, int* __restrict__ order,
                          int* __restrict__ csort) {
    __shared__ int sbase[1024];
    __shared__ int wtot[4];
    int t = threadIdx.x;
    int lane = t & 63, wv = t >> 6;
    int c4[4];
    #pragma unroll
    for (int j = 0; j < 4; ++j) c4[j] = cnt[4 * t + j];
    int s = c4[0] + c4[1] + c4[2] + c4[3];
    int ps = s;
    #pragma unroll
    for (int m = 1; m < 64; m <<= 1) {
        int o = __shfl_up(ps, m);
        if (lane >= m) ps += o;
    }
    if (lane == 63) wtot[wv] = ps;
    __syncthreads();
    int woff = 0;
    for (int i = 0; i < 4; ++i) if (i < wv) woff += wtot[i];
    int run = woff + ps - s;
    #pragma unroll
    for (int j = 0; j < 4; ++j) {
        sbase[4 * t + j] = run;    // exclusive base of code 4t+j
        run += c4[j];
    }
    __syncthreads();

    int n = blockIdx.x * 256 + t;
    int c = code_i[n];
    int pos = sbase[c] + atomicAdd(zc + c, 1);
    order[pos] = n;
    csort[pos] = c;
}

// -------------------------------------------------------------------
// UNIFORM-WORK fused segment-sum + dequant/ST/ssq, 256 threads:
// block i owns sorted slots [32i,32i+32) as TWO independent 16-slot
// halves (tid>>7), each with its own running-sum flush chain (flushes
// are atomic -> correct regardless of which half flushes).
__launch_bounds__(256)
__global__ void k_segdeq(const float* __restrict__ x, const float* __restrict__ Et,
                         const int* __restrict__ order, const int* __restrict__ csort,
                         float* __restrict__ part1, float* __restrict__ outq,
                         float* __restrict__ ssqp) {
    __shared__ int sn[WSEG], sc[WSEG];
    __shared__ float wsum[4];
    int tid = threadIdx.x;
    int d = tid & 127;
    int h = tid >> 7;                       // half 0/1
    int i0 = blockIdx.x * WSEG;
    if (tid < WSEG) { sn[tid] = order[i0 + tid]; sc[tid] = csort[i0 + tid]; }
    __syncthreads();
    int s0 = h * 16;
    int cprev = sc[s0];
    float eq = Et[(size_t)cprev * D_ + d];
    float acc = 0.f, ssql = 0.f;
    float xv = x[(size_t)sn[s0] * D_ + d];
    #pragma unroll 4
    for (int j = 0; j < 16; ++j) {
        int sj = s0 + j;
        float xn = (j < 15) ? x[(size_t)sn[sj + 1] * D_ + d] : 0.f;  // prefetch
        int c = sc[sj];
        if (c != cprev) {                      // wave-uniform branch
            atomicAdd(&part1[(size_t)cprev * D_ + d], acc);
            acc = 0.f;
            eq = Et[(size_t)c * D_ + d];
            cprev = c;
        }
        float qv = xv + (eq - xv);             // reference fp32 rounding
        outq[(size_t)sn[sj] * D_ + d] = qv;
        float t = qv - xv;
        ssql = fmaf(t, t, ssql);
        acc += xv;
        xv = xn;
    }
    atomicAdd(&part1[(size_t)cprev * D_ + d], acc);

    // block-reduce ssql (4 waves of 64) -> one global atomic
    #pragma unroll
    for (int off = 32; off > 0; off >>= 1) ssql += __shfl_down(ssql, off);
    if ((tid & 63) == 0) wsum[tid >> 6] = ssql;
    __syncthreads();
    if (tid == 0) atomicAdd(ssqp, (wsum[0] + wsum[1]) + (wsum[2] + wsum[3]));
}

// -------------------------------------------------------------------
// fused stats + embed: each block redundantly reduces n; block 0 also
// writes out_ncs + out_diff. Then EMA mean + divide for its 256 elems.
__launch_bounds__(256)
__global__ void k_embed(const float* __restrict__ em, const float* __restrict__ part1,
                        const int* __restrict__ cnt, const float* __restrict__ csz,
                        const float* __restrict__ ssqp, float* __restrict__ out_nmean,
                        float* __restrict__ out_nemb, float* __restrict__ out_ncs,
                        float* __restrict__ out_diff) {
    int tid = threadIdx.x;
    __shared__ float red[256];

    // ---- n = sum_k ncs_k (redundant per block) ----
    float ls = 0.f;
    for (int j = tid; j < K_; j += 256) ls += csz[j] * DECAY_ + OMD_ * (float)cnt[j];
    red[tid] = ls;
    __syncthreads();
    for (int off = 128; off > 0; off >>= 1) {
        if (tid < off) red[tid] += red[tid + off];
        __syncthreads();
    }
    float n = red[0];
    __syncthreads();

    if (blockIdx.x == 0) {
        for (int j = tid; j < K_; j += 256)
            out_ncs[j] = csz[j] * DECAY_ + OMD_ * (float)cnt[j];
        if (tid == 0) *out_diff = VQC_ * ssqp[0] / (float)(N_ * D_);
    }

    int i = blockIdx.x * 256 + tid;           // over D*K, layout [D][K]
    int k = i & (K_ - 1);
    int d = i >> 10;
    float ncs_k = csz[k] * DECAY_ + OMD_ * (float)cnt[k];
    float csk = (ncs_k + EPS_) / (n + (float)K_ * EPS_) * n;
    float es = part1[(size_t)k * D_ + d];
    float nm = em[i] * DECAY_ + OMD_ * es;
    out_nmean[i] = nm;
    out_nemb[i]  = nm / csk;
}

// -------------------------------------------------------------------
extern "C" void kernel_launch(void* const* d_in, const int* in_sizes, int n_in,
                              void* d_out, int out_size, void* d_ws, size_t ws_size,
                              hipStream_t stream) {
    const float* x   = (const float*)d_in[0];   // [16,4096,128]
    const float* E   = (const float*)d_in[1];   // [128,1024]
    const float* csz = (const float*)d_in[2];   // [1024]
    const float* em  = (const float*)d_in[3];   // [128,1024]
    float* out = (float*)d_out;
    float* W   = (float*)d_ws;

    int*   code_i = (int*)(W + WOFF_CODE);
    float* e2     = W + WOFF_E2;
    int*   cnt    = (int*)(W + WOFF_CNT);
    float* ssqp   = W + WOFF_SSQ;
    int*   rcnt   = (int*)(W + WOFF_RCNT);
    int*   zc     = (int*)(W + WOFF_CURS);
    int*   order  = (int*)(W + WOFF_ORDER);
    float* Et     = W + WOFF_ET;
    float* part1  = W + WOFF_PART;
    int*   csort  = (int*)(W + WOFF_CSORT);
    int*   rlist  = (int*)(W + WOFF_RLIST);
    unsigned short* Ef = (unsigned short*)(W + WOFF_EF);

    k_prep<<<64, 256, 0, stream>>>(E, Et, Ef, e2, cnt, zc, part1);
    k_argmin_mfma<<<N_ / 128, 512, 0, stream>>>(x, Ef, e2, code_i,
                                                out + OOFF_CODE, cnt, rcnt, rlist, Et);
    k_fix<<<1024, 256, 0, stream>>>(x, Et, e2, rcnt, rlist, code_i, out + OOFF_CODE, cnt);
    k_scatter<<<N_ / 256, 256, 0, stream>>>(cnt, code_i, zc, order, csort);
    k_segdeq<<<N_ / WSEG, 256, 0, stream>>>(x, Et, order, csort, part1,
                                            out + OOFF_Q, ssqp);
    k_embed<<<(D_ * K_) / 256, 256, 0, stream>>>(em, part1, cnt, csz, ssqp,
                                                 out + OOFF_NMEAN, out + OOFF_NEMB,
                                                 out + OOFF_NCS, out + OOFF_DIFF);
}